// Round 1
// baseline (2047.932 us; speedup 1.0000x reference)
//
#include <hip/hip_runtime.h>
#include <hip/hip_bf16.h>
#include <math.h>

#define H 128

// ---------------- CSR build ----------------

__global__ __launch_bounds__(256) void count_kernel(const int* __restrict__ edges, int E,
                                                    int* __restrict__ cnt) {
    int e = blockIdx.x * 256 + threadIdx.x;
    if (e < E) atomicAdd(&cnt[edges[E + e]], 1);
}

// cnt_then_cursor: on entry holds counts; on exit holds row start offsets (cursor for fill).
__global__ __launch_bounds__(1024) void scan_kernel(int* __restrict__ cnt_then_cursor,
                                                    int* __restrict__ rowptr, int n) {
    __shared__ int sums[1024];
    int t = threadIdx.x;
    int chunk = (n + 1023) >> 10;
    int beg = t * chunk;
    int end = beg + chunk; if (end > n) end = n;
    int s = 0;
    for (int i = beg; i < end; ++i) s += cnt_then_cursor[i];
    sums[t] = s;
    __syncthreads();
    if (t == 0) {
        int run = 0;
        for (int i = 0; i < 1024; ++i) { int v = sums[i]; sums[i] = run; run += v; }
        rowptr[n] = run;
    }
    __syncthreads();
    int off = sums[t];
    for (int i = beg; i < end; ++i) {
        int v = cnt_then_cursor[i];
        rowptr[i] = off;
        cnt_then_cursor[i] = off;
        off += v;
    }
}

__global__ __launch_bounds__(256) void fill_kernel(const int* __restrict__ edges, int E,
                                                   int* __restrict__ cursor, int* __restrict__ col) {
    int e = blockIdx.x * 256 + threadIdx.x;
    if (e < E) {
        int src = edges[e];
        int dst = edges[E + e];
        col[atomicAdd(&cursor[dst], 1)] = src;
    }
}

// ---------------- segment mean (gather over CSR) ----------------
// one wave per dst node; lane covers 2 channels (float2) -> 64 lanes * 8B = full 512B row

__global__ __launch_bounds__(256) void agg_mean_kernel(const float* __restrict__ x,
                                                       const int* __restrict__ rowptr,
                                                       const int* __restrict__ col,
                                                       float* __restrict__ out, int n_dst) {
    int w = (blockIdx.x << 2) + (threadIdx.x >> 6);
    int lane = threadIdx.x & 63;
    if (w >= n_dst) return;
    int beg = rowptr[w], end = rowptr[w + 1];
    float ax = 0.f, ay = 0.f;
    for (int e = beg; e < end; ++e) {
        int s = col[e];
        float2 v = *(const float2*)&x[(size_t)s * H + lane * 2];
        ax += v.x; ay += v.y;
    }
    int c = end - beg; if (c < 1) c = 1;
    float inv = 1.0f / (float)c;
    float2 r; r.x = ax * inv; r.y = ay * inv;
    *(float2*)&out[(size_t)w * H + lane * 2] = r;
}

// ---------------- fused multi-input GEMM ----------------
// out[r, :] = sum_m A_m[r, :] @ (W_m_a + W_m_b) + bias0 + bias1, optional leaky relu.
// Block computes 64 rows x 128 cols. Thread: 8 rows x 4 cols.
// In-place safe when out == A_m: each block stages (reads) only its own 64 rows, writes at end.

__device__ __forceinline__ void fma4(float4& acc, float s, const float4& w) {
    acc.x = fmaf(s, w.x, acc.x);
    acc.y = fmaf(s, w.y, acc.y);
    acc.z = fmaf(s, w.z, acc.z);
    acc.w = fmaf(s, w.w, acc.w);
}

template <int NIN>
__global__ __launch_bounds__(256) void gemm_fused(
    const float* __restrict__ A0, const float* __restrict__ A1, const float* __restrict__ A2,
    const float* __restrict__ W0a, const float* __restrict__ W0b,
    const float* __restrict__ W1a, const float* __restrict__ W1b,
    const float* __restrict__ W2a, const float* __restrict__ W2b,
    const float* __restrict__ b0, const float* __restrict__ b1,
    float* __restrict__ out, int n_rows, int relu) {
    __shared__ float As[64 * H];
    const int tid = threadIdx.x;
    const int r0 = blockIdx.x * 64;
    const int cg = (tid & 31) * 4;   // col start (0..124)
    const int rg = (tid >> 5) * 8;   // row start within block (0..56)

    float4 bias = *(const float4*)&b0[cg];
    if (b1) {
        float4 t = *(const float4*)&b1[cg];
        bias.x += t.x; bias.y += t.y; bias.z += t.z; bias.w += t.w;
    }
    float4 acc[8];
#pragma unroll
    for (int r = 0; r < 8; ++r) acc[r] = bias;

    const float* Aarr[3]  = {A0, A1, A2};
    const float* Waarr[3] = {W0a, W1a, W2a};
    const float* Wbarr[3] = {W0b, W1b, W2b};

    for (int m = 0; m < NIN; ++m) {
        const float* __restrict__ A = Aarr[m];
        __syncthreads();
#pragma unroll
        for (int i = 0; i < 8; ++i) {
            int f = tid + i * 256;          // float4 index 0..2047
            int row = f >> 5;               // 32 float4 per row
            int cc = (f & 31) * 4;
            int gr = r0 + row;
            if (gr >= n_rows) gr = n_rows - 1;
            *(float4*)&As[row * H + cc] = *(const float4*)&A[(size_t)gr * H + cc];
        }
        __syncthreads();
        const float* __restrict__ Wa = Waarr[m];
        const float* __restrict__ Wb = Wbarr[m];
        for (int k = 0; k < H; k += 4) {
            float4 w0 = *(const float4*)&Wa[(k + 0) * H + cg];
            float4 w1 = *(const float4*)&Wa[(k + 1) * H + cg];
            float4 w2 = *(const float4*)&Wa[(k + 2) * H + cg];
            float4 w3 = *(const float4*)&Wa[(k + 3) * H + cg];
            if (Wb) {
                float4 u0 = *(const float4*)&Wb[(k + 0) * H + cg];
                float4 u1 = *(const float4*)&Wb[(k + 1) * H + cg];
                float4 u2 = *(const float4*)&Wb[(k + 2) * H + cg];
                float4 u3 = *(const float4*)&Wb[(k + 3) * H + cg];
                w0.x += u0.x; w0.y += u0.y; w0.z += u0.z; w0.w += u0.w;
                w1.x += u1.x; w1.y += u1.y; w1.z += u1.z; w1.w += u1.w;
                w2.x += u2.x; w2.y += u2.y; w2.z += u2.z; w2.w += u2.w;
                w3.x += u3.x; w3.y += u3.y; w3.z += u3.z; w3.w += u3.w;
            }
#pragma unroll
            for (int r = 0; r < 8; ++r) {
                float4 a = *(const float4*)&As[(rg + r) * H + k];
                fma4(acc[r], a.x, w0);
                fma4(acc[r], a.y, w1);
                fma4(acc[r], a.z, w2);
                fma4(acc[r], a.w, w3);
            }
        }
    }

#pragma unroll
    for (int r = 0; r < 8; ++r) {
        int gr = r0 + rg + r;
        if (gr < n_rows) {
            float4 v = acc[r];
            if (relu) {
                v.x = v.x > 0.f ? v.x : 0.01f * v.x;
                v.y = v.y > 0.f ? v.y : 0.01f * v.y;
                v.z = v.z > 0.f ? v.z : 0.01f * v.z;
                v.w = v.w > 0.f ? v.w : 0.01f * v.w;
            }
            *(float4*)&out[(size_t)gr * H + cg] = v;
        }
    }
}

// ---------------- edge decoder: sigmoid(dot(xp[i], xg[j])) ----------------
// 16 lanes per edge, each lane covers 8 channels (2x float4), xor-reduce within 16.

__global__ __launch_bounds__(256) void scores_kernel(const float* __restrict__ xp,
                                                     const float* __restrict__ xg,
                                                     const int* __restrict__ eli, int E,
                                                     float* __restrict__ out) {
    int lane16 = threadIdx.x & 15;
    int sub = threadIdx.x >> 4;     // 16 edges per block
    int e = blockIdx.x * 16 + sub;
    if (e >= E) return;
    int ip = eli[e];
    int ig = eli[E + e];
    const float4* p = (const float4*)&xp[(size_t)ip * H];
    const float4* g = (const float4*)&xg[(size_t)ig * H];
    float4 a0 = p[lane16], a1 = p[lane16 + 16];
    float4 b0 = g[lane16], b1 = g[lane16 + 16];
    float s = a0.x * b0.x + a0.y * b0.y + a0.z * b0.z + a0.w * b0.w
            + a1.x * b1.x + a1.y * b1.y + a1.z * b1.z + a1.w * b1.w;
#pragma unroll
    for (int off = 8; off; off >>= 1) s += __shfl_xor(s, off, 16);
    if (lane16 == 0) out[e] = 1.0f / (1.0f + expf(-s));
}

// ---------------- host ----------------

extern "C" void kernel_launch(void* const* d_in, const int* in_sizes, int n_in,
                              void* d_out, int out_size, void* d_ws, size_t ws_size,
                              hipStream_t stream) {
    const float* x_pheno = (const float*)d_in[0];
    const float* x_gene  = (const float*)d_in[1];
    const float* Wl_isa  = (const float*)d_in[2];
    const float* bl_isa  = (const float*)d_in[3];
    const float* Wr_isa  = (const float*)d_in[4];
    const float* Wl_rel  = (const float*)d_in[5];
    const float* bl_rel  = (const float*)d_in[6];
    const float* Wr_rel  = (const float*)d_in[7];
    const float* Wl_rev  = (const float*)d_in[8];
    const float* bl_rev  = (const float*)d_in[9];
    const float* Wr_rev  = (const float*)d_in[10];
    const int* e_isa = (const int*)d_in[11];
    const int* e_rel = (const int*)d_in[12];
    const int* e_rev = (const int*)d_in[13];
    const int* e_lbl = (const int*)d_in[14];
    const int E_isa = in_sizes[11] / 2;
    const int E_rel = in_sizes[12] / 2;
    const int E_rev = in_sizes[13] / 2;
    const int E_lbl = in_sizes[14] / 2;
    const int NP = in_sizes[0] / H;
    const int NG = in_sizes[1] / H;
    const int NMAX = NP > NG ? NP : NG;

    char* ws = (char*)d_ws;
    auto alloc = [&](size_t bytes) -> char* {
        char* p = ws;
        ws += (bytes + 255) & ~(size_t)255;
        return p;
    };
    float* B[5];
    for (int i = 0; i < 5; ++i) B[i] = (float*)alloc((size_t)NMAX * H * sizeof(float));
    int* rp_isa = (int*)alloc((size_t)(NP + 1) * 4);
    int* rp_rel = (int*)alloc((size_t)(NG + 1) * 4);
    int* rp_rev = (int*)alloc((size_t)(NP + 1) * 4);
    int* cur_isa = (int*)alloc((size_t)NP * 4);
    int* cur_rel = (int*)alloc((size_t)NG * 4);
    int* cur_rev = (int*)alloc((size_t)NP * 4);
    int* col_isa = (int*)alloc((size_t)E_isa * 4);
    int* col_rel = (int*)alloc((size_t)E_rel * 4);
    int* col_rev = (int*)alloc((size_t)E_rev * 4);

    // ---- CSR build (rebuilt every call; ws is re-poisoned by the harness) ----
    hipMemsetAsync(cur_isa, 0, (size_t)NP * 4, stream);
    hipMemsetAsync(cur_rel, 0, (size_t)NG * 4, stream);
    hipMemsetAsync(cur_rev, 0, (size_t)NP * 4, stream);
    count_kernel<<<(E_isa + 255) / 256, 256, 0, stream>>>(e_isa, E_isa, cur_isa);
    count_kernel<<<(E_rel + 255) / 256, 256, 0, stream>>>(e_rel, E_rel, cur_rel);
    count_kernel<<<(E_rev + 255) / 256, 256, 0, stream>>>(e_rev, E_rev, cur_rev);
    scan_kernel<<<1, 1024, 0, stream>>>(cur_isa, rp_isa, NP);
    scan_kernel<<<1, 1024, 0, stream>>>(cur_rel, rp_rel, NG);
    scan_kernel<<<1, 1024, 0, stream>>>(cur_rev, rp_rev, NP);
    fill_kernel<<<(E_isa + 255) / 256, 256, 0, stream>>>(e_isa, E_isa, cur_isa, col_isa);
    fill_kernel<<<(E_rel + 255) / 256, 256, 0, stream>>>(e_rel, E_rel, cur_rel, col_rel);
    fill_kernel<<<(E_rev + 255) / 256, 256, 0, stream>>>(e_rev, E_rev, cur_rev, col_rev);

    // ---- 3 layers ----
    // buffer schedule: layer0 M1=B0 M2=B1 M3=B2; layer1 M1=B3 M2=B1 M3=B4; layer2 M1=B0 M2=B1 M3=B2
    int mi[3] = {0, 3, 0}, mv[3] = {1, 1, 1}, mr[3] = {2, 4, 2};
    const float* xp = x_pheno;
    const float* xg = x_gene;
    for (int l = 0; l < 3; ++l) {
        float* M1 = B[mi[l]];
        float* M2 = B[mv[l]];
        float* M3 = B[mr[l]];
        agg_mean_kernel<<<(NP + 3) / 4, 256, 0, stream>>>(xp, rp_isa, col_isa, M1, NP);
        agg_mean_kernel<<<(NP + 3) / 4, 256, 0, stream>>>(xg, rp_rev, col_rev, M2, NP);
        agg_mean_kernel<<<(NG + 3) / 4, 256, 0, stream>>>(xp, rp_rel, col_rel, M3, NG);
        int relu = (l < 2) ? 1 : 0;
        const float* Wli = Wl_isa + (size_t)l * H * H;
        const float* bli = bl_isa + (size_t)l * H;
        const float* Wri = Wr_isa + (size_t)l * H * H;
        const float* Wlv = Wl_rev + (size_t)l * H * H;
        const float* blv = bl_rev + (size_t)l * H;
        const float* Wrv = Wr_rev + (size_t)l * H * H;
        const float* Wlr = Wl_rel + (size_t)l * H * H;
        const float* blr = bl_rel + (size_t)l * H;
        const float* Wrr = Wr_rel + (size_t)l * H * H;
        // new_p = M1@Wl_isa + M2@Wl_rev + xp@(Wr_isa+Wr_rev) + bl_isa + bl_rev  -> M1 (in-place)
        gemm_fused<3><<<(NP + 63) / 64, 256, 0, stream>>>(
            M1, M2, xp, Wli, nullptr, Wlv, nullptr, Wri, Wrv, bli, blv, M1, NP, relu);
        // new_g = M3@Wl_rel + xg@Wr_rel + bl_rel  -> M3 (in-place)
        gemm_fused<2><<<(NG + 63) / 64, 256, 0, stream>>>(
            M3, xg, nullptr, Wlr, nullptr, Wrr, nullptr, nullptr, nullptr, blr, nullptr, M3, NG, relu);
        xp = M1;
        xg = M3;
    }

    // ---- decoder ----
    scores_kernel<<<(E_lbl + 15) / 16, 256, 0, stream>>>(xp, xg, e_lbl, E_lbl, (float*)d_out);
}

// Round 2
// 1756.725 us; speedup vs baseline: 1.1658x; 1.1658x over previous
//
#include <hip/hip_runtime.h>
#include <hip/hip_bf16.h>
#include <math.h>

#define H 128

// ---------------- CSR build ----------------
// Counts for all 3 edge types live in ONE concatenated buffer [NP(isa) | NG(rel) | NP(rev)].
// One hierarchical scan produces GLOBAL offsets -> one shared col buffer, rowptr slices per type.

__global__ __launch_bounds__(256) void count_kernel(const int* __restrict__ edges, int E,
                                                    int* __restrict__ cnt) {
    int e = blockIdx.x * 256 + threadIdx.x;
    if (e < E) atomicAdd(&cnt[edges[E + e]], 1);
}

// pass1: per-block (1024 elems) sums
__global__ __launch_bounds__(256) void scan_pass1(const int* __restrict__ cnt, int n,
                                                  int* __restrict__ partial) {
    int base = blockIdx.x * 1024 + threadIdx.x * 4;
    int s = 0;
    if (base + 3 < n) {
        int4 v = *(const int4*)&cnt[base];
        s = v.x + v.y + v.z + v.w;
    } else {
        for (int i = 0; i < 4; ++i) if (base + i < n) s += cnt[base + i];
    }
    __shared__ int red[256];
    red[threadIdx.x] = s;
    __syncthreads();
    for (int off = 128; off; off >>= 1) {
        if (threadIdx.x < off) red[threadIdx.x] += red[threadIdx.x + off];
        __syncthreads();
    }
    if (threadIdx.x == 0) partial[blockIdx.x] = red[0];
}

// pass2: single block exclusive-scans the partials (nb <= 1024), writes grand total to rowptr[n]
__global__ __launch_bounds__(1024) void scan_pass2(int* __restrict__ partial, int nb,
                                                   int* __restrict__ total_out) {
    __shared__ int sh[1024];
    int t = threadIdx.x;
    int v = (t < nb) ? partial[t] : 0;
    sh[t] = v;
    __syncthreads();
    for (int off = 1; off < 1024; off <<= 1) {
        int u = (t >= off) ? sh[t - off] : 0;
        __syncthreads();
        sh[t] += u;
        __syncthreads();
    }
    if (t < nb) partial[t] = sh[t] - v;   // exclusive
    if (t == 1023) *total_out = sh[1023];
}

// pass3: per-block local exclusive scan + block offset; writes rowptr and cursor
__global__ __launch_bounds__(256) void scan_pass3(const int* __restrict__ cnt, int n,
                                                  const int* __restrict__ partial,
                                                  int* __restrict__ rowptr,
                                                  int* __restrict__ cursor) {
    int t = threadIdx.x;
    int base = blockIdx.x * 1024 + t * 4;
    int v[4];
    int s = 0;
    for (int i = 0; i < 4; ++i) {
        v[i] = (base + i < n) ? cnt[base + i] : 0;
        s += v[i];
    }
    __shared__ int sh[256];
    sh[t] = s;
    __syncthreads();
    for (int off = 1; off < 256; off <<= 1) {
        int u = (t >= off) ? sh[t - off] : 0;
        __syncthreads();
        sh[t] += u;
        __syncthreads();
    }
    int run = partial[blockIdx.x] + sh[t] - s;
    for (int i = 0; i < 4; ++i) {
        int idx = base + i;
        if (idx < n) {
            rowptr[idx] = run;
            cursor[idx] = run;
            run += v[i];
        }
    }
}

__global__ __launch_bounds__(256) void fill_kernel(const int* __restrict__ edges, int E,
                                                   int* __restrict__ cursor, int* __restrict__ col) {
    int e = blockIdx.x * 256 + threadIdx.x;
    if (e < E) {
        int src = edges[e];
        int dst = edges[E + e];
        col[atomicAdd(&cursor[dst], 1)] = src;
    }
}

// ---------------- Wsum = Wr_isa + Wr_rev (all 3 layers), float4 ----------------

__global__ __launch_bounds__(256) void add_w_kernel(const float* __restrict__ a,
                                                    const float* __restrict__ b,
                                                    float* __restrict__ o, int n4) {
    int i = blockIdx.x * 256 + threadIdx.x;
    if (i < n4) {
        float4 x = ((const float4*)a)[i];
        float4 y = ((const float4*)b)[i];
        x.x += y.x; x.y += y.y; x.z += y.z; x.w += y.w;
        ((float4*)o)[i] = x;
    }
}

// ---------------- segment mean (gather over CSR) ----------------
// one wave per dst node; lane covers 2 channels (float2) -> 64 lanes * 8B = full 512B row

__global__ __launch_bounds__(256) void agg_mean_kernel(const float* __restrict__ x,
                                                       const int* __restrict__ rowptr,
                                                       const int* __restrict__ col,
                                                       float* __restrict__ out, int n_dst) {
    int w = (blockIdx.x << 2) + (threadIdx.x >> 6);
    int lane = threadIdx.x & 63;
    if (w >= n_dst) return;
    int beg = rowptr[w], end = rowptr[w + 1];
    float ax = 0.f, ay = 0.f;
    for (int e = beg; e < end; ++e) {
        int s = col[e];
        float2 v = *(const float2*)&x[(size_t)s * H + lane * 2];
        ax += v.x; ay += v.y;
    }
    int c = end - beg; if (c < 1) c = 1;
    float inv = 1.0f / (float)c;
    float2 r; r.x = ax * inv; r.y = ay * inv;
    *(float2*)&out[(size_t)w * H + lane * 2] = r;
}

// ---------------- fused multi-input GEMM ----------------
// out[r,:] = sum_m A_m[r,:] @ W_m + b0 + b1, optional leaky relu.
// Block: 64 rows x 128 cols. Thread: 8 rows x 4 cols.
// In-place safe when out == A_m: block stages (reads) only its own 64 rows, writes at end.

__device__ __forceinline__ void fma4(float4& acc, float s, const float4& w) {
    acc.x = fmaf(s, w.x, acc.x);
    acc.y = fmaf(s, w.y, acc.y);
    acc.z = fmaf(s, w.z, acc.z);
    acc.w = fmaf(s, w.w, acc.w);
}

template <int NIN>
__global__ __launch_bounds__(256) void gemm_fused(
    const float* __restrict__ A0, const float* __restrict__ A1, const float* __restrict__ A2,
    const float* __restrict__ W0, const float* __restrict__ W1, const float* __restrict__ W2,
    const float* __restrict__ b0, const float* __restrict__ b1,
    float* __restrict__ out, int n_rows, int relu) {
    __shared__ float As[64 * H];
    const int tid = threadIdx.x;
    const int r0 = blockIdx.x * 64;
    const int cg = (tid & 31) * 4;   // col start (0..124)
    const int rg = (tid >> 5) * 8;   // row start within block (0..56)

    float4 bias = *(const float4*)&b0[cg];
    if (b1) {
        float4 t = *(const float4*)&b1[cg];
        bias.x += t.x; bias.y += t.y; bias.z += t.z; bias.w += t.w;
    }
    float4 acc[8];
#pragma unroll
    for (int r = 0; r < 8; ++r) acc[r] = bias;

    const float* Aarr[3] = {A0, A1, A2};
    const float* Warr[3] = {W0, W1, W2};

    for (int m = 0; m < NIN; ++m) {
        const float* __restrict__ A = Aarr[m];
        __syncthreads();
#pragma unroll
        for (int i = 0; i < 8; ++i) {
            int f = tid + i * 256;          // float4 index 0..2047
            int row = f >> 5;               // 32 float4 per row
            int cc = (f & 31) * 4;
            int gr = r0 + row;
            if (gr >= n_rows) gr = n_rows - 1;
            *(float4*)&As[row * H + cc] = *(const float4*)&A[(size_t)gr * H + cc];
        }
        __syncthreads();
        const float* __restrict__ W = Warr[m];
        for (int k = 0; k < H; k += 4) {
            float4 w0 = *(const float4*)&W[(k + 0) * H + cg];
            float4 w1 = *(const float4*)&W[(k + 1) * H + cg];
            float4 w2 = *(const float4*)&W[(k + 2) * H + cg];
            float4 w3 = *(const float4*)&W[(k + 3) * H + cg];
#pragma unroll
            for (int r = 0; r < 8; ++r) {
                float4 a = *(const float4*)&As[(rg + r) * H + k];
                fma4(acc[r], a.x, w0);
                fma4(acc[r], a.y, w1);
                fma4(acc[r], a.z, w2);
                fma4(acc[r], a.w, w3);
            }
        }
    }

#pragma unroll
    for (int r = 0; r < 8; ++r) {
        int gr = r0 + rg + r;
        if (gr < n_rows) {
            float4 v = acc[r];
            if (relu) {
                v.x = v.x > 0.f ? v.x : 0.01f * v.x;
                v.y = v.y > 0.f ? v.y : 0.01f * v.y;
                v.z = v.z > 0.f ? v.z : 0.01f * v.z;
                v.w = v.w > 0.f ? v.w : 0.01f * v.w;
            }
            *(float4*)&out[(size_t)gr * H + cg] = v;
        }
    }
}

// ---------------- edge decoder: sigmoid(dot(xp[i], xg[j])) ----------------

__global__ __launch_bounds__(256) void scores_kernel(const float* __restrict__ xp,
                                                     const float* __restrict__ xg,
                                                     const int* __restrict__ eli, int E,
                                                     float* __restrict__ out) {
    int lane16 = threadIdx.x & 15;
    int sub = threadIdx.x >> 4;     // 16 edges per block
    int e = blockIdx.x * 16 + sub;
    if (e >= E) return;
    int ip = eli[e];
    int ig = eli[E + e];
    const float4* p = (const float4*)&xp[(size_t)ip * H];
    const float4* g = (const float4*)&xg[(size_t)ig * H];
    float4 a0 = p[lane16], a1 = p[lane16 + 16];
    float4 b0 = g[lane16], b1 = g[lane16 + 16];
    float s = a0.x * b0.x + a0.y * b0.y + a0.z * b0.z + a0.w * b0.w
            + a1.x * b1.x + a1.y * b1.y + a1.z * b1.z + a1.w * b1.w;
#pragma unroll
    for (int off = 8; off; off >>= 1) s += __shfl_xor(s, off, 16);
    if (lane16 == 0) out[e] = 1.0f / (1.0f + expf(-s));
}

// ---------------- host ----------------

extern "C" void kernel_launch(void* const* d_in, const int* in_sizes, int n_in,
                              void* d_out, int out_size, void* d_ws, size_t ws_size,
                              hipStream_t stream) {
    const float* x_pheno = (const float*)d_in[0];
    const float* x_gene  = (const float*)d_in[1];
    const float* Wl_isa  = (const float*)d_in[2];
    const float* bl_isa  = (const float*)d_in[3];
    const float* Wr_isa  = (const float*)d_in[4];
    const float* Wl_rel  = (const float*)d_in[5];
    const float* bl_rel  = (const float*)d_in[6];
    const float* Wr_rel  = (const float*)d_in[7];
    const float* Wl_rev  = (const float*)d_in[8];
    const float* bl_rev  = (const float*)d_in[9];
    const float* Wr_rev  = (const float*)d_in[10];
    const int* e_isa = (const int*)d_in[11];
    const int* e_rel = (const int*)d_in[12];
    const int* e_rev = (const int*)d_in[13];
    const int* e_lbl = (const int*)d_in[14];
    const int E_isa = in_sizes[11] / 2;
    const int E_rel = in_sizes[12] / 2;
    const int E_rev = in_sizes[13] / 2;
    const int E_lbl = in_sizes[14] / 2;
    const int NP = in_sizes[0] / H;
    const int NG = in_sizes[1] / H;
    const int NMAX = NP > NG ? NP : NG;
    const int n_tot = NP + NG + NP;            // concatenated count/rowptr space
    const int E_tot = E_isa + E_rel + E_rev;
    const int nb = (n_tot + 1023) / 1024;      // scan blocks (<=1024)

    char* ws = (char*)d_ws;
    auto alloc = [&](size_t bytes) -> char* {
        char* p = ws;
        ws += (bytes + 255) & ~(size_t)255;
        return p;
    };
    float* B[5];
    for (int i = 0; i < 5; ++i) B[i] = (float*)alloc((size_t)NMAX * H * sizeof(float));
    int* cnt    = (int*)alloc((size_t)n_tot * 4);        // counts, then consumed by scan
    int* rowptr = (int*)alloc((size_t)(n_tot + 1) * 4);  // global exclusive offsets
    int* cursor = (int*)alloc((size_t)n_tot * 4);        // mutable copy for fill
    int* col    = (int*)alloc((size_t)E_tot * 4);        // shared column buffer
    int* partial = (int*)alloc((size_t)1024 * 4);
    float* Wsum = (float*)alloc((size_t)3 * H * H * sizeof(float));  // Wr_isa + Wr_rev

    int* cnt_isa = cnt;             // dst in [0,NP)
    int* cnt_rel = cnt + NP;        // dst in [0,NG)
    int* cnt_rev = cnt + NP + NG;   // dst in [0,NP)
    const int* rp_isa = rowptr;
    const int* rp_rel = rowptr + NP;
    const int* rp_rev = rowptr + NP + NG;

    // ---- CSR build (every call; ws is re-poisoned by the harness) ----
    hipMemsetAsync(cnt, 0, (size_t)n_tot * 4, stream);
    count_kernel<<<(E_isa + 255) / 256, 256, 0, stream>>>(e_isa, E_isa, cnt_isa);
    count_kernel<<<(E_rel + 255) / 256, 256, 0, stream>>>(e_rel, E_rel, cnt_rel);
    count_kernel<<<(E_rev + 255) / 256, 256, 0, stream>>>(e_rev, E_rev, cnt_rev);
    scan_pass1<<<nb, 256, 0, stream>>>(cnt, n_tot, partial);
    scan_pass2<<<1, 1024, 0, stream>>>(partial, nb, &rowptr[n_tot]);
    scan_pass3<<<nb, 256, 0, stream>>>(cnt, n_tot, partial, rowptr, cursor);
    fill_kernel<<<(E_isa + 255) / 256, 256, 0, stream>>>(e_isa, E_isa, cursor, col);
    fill_kernel<<<(E_rel + 255) / 256, 256, 0, stream>>>(e_rel, E_rel, cursor + NP, col);
    fill_kernel<<<(E_rev + 255) / 256, 256, 0, stream>>>(e_rev, E_rev, cursor + NP + NG, col);

    // ---- Wsum precompute ----
    add_w_kernel<<<(3 * H * H / 4 + 255) / 256, 256, 0, stream>>>(Wr_isa, Wr_rev, Wsum, 3 * H * H / 4);

    // ---- 3 layers ----
    // buffers: layer0 M1=B0 M2=B1 M3=B2; layer1 M1=B3 M2=B1 M3=B4; layer2 M1=B0 M2=B1 M3=B2
    int mi[3] = {0, 3, 0}, mv[3] = {1, 1, 1}, mr[3] = {2, 4, 2};
    const float* xp = x_pheno;
    const float* xg = x_gene;
    for (int l = 0; l < 3; ++l) {
        float* M1 = B[mi[l]];
        float* M2 = B[mv[l]];
        float* M3 = B[mr[l]];
        agg_mean_kernel<<<(NP + 3) / 4, 256, 0, stream>>>(xp, rp_isa, col, M1, NP);
        agg_mean_kernel<<<(NP + 3) / 4, 256, 0, stream>>>(xg, rp_rev, col, M2, NP);
        agg_mean_kernel<<<(NG + 3) / 4, 256, 0, stream>>>(xp, rp_rel, col, M3, NG);
        int relu = (l < 2) ? 1 : 0;
        const float* Wli = Wl_isa + (size_t)l * H * H;
        const float* bli = bl_isa + (size_t)l * H;
        const float* Wlv = Wl_rev + (size_t)l * H * H;
        const float* blv = bl_rev + (size_t)l * H;
        const float* Wlr = Wl_rel + (size_t)l * H * H;
        const float* blr = bl_rel + (size_t)l * H;
        const float* Wrr = Wr_rel + (size_t)l * H * H;
        const float* Wsl = Wsum + (size_t)l * H * H;
        // new_p = M1@Wl_isa + M2@Wl_rev + xp@(Wr_isa+Wr_rev) + bl_isa + bl_rev -> M1 (in-place)
        gemm_fused<3><<<(NP + 63) / 64, 256, 0, stream>>>(
            M1, M2, xp, Wli, Wlv, Wsl, bli, blv, M1, NP, relu);
        // new_g = M3@Wl_rel + xg@Wr_rel + bl_rel -> M3 (in-place)
        gemm_fused<2><<<(NG + 63) / 64, 256, 0, stream>>>(
            M3, xg, nullptr, Wlr, Wrr, nullptr, blr, nullptr, M3, NG, relu);
        xp = M1;
        xg = M3;
    }

    // ---- decoder ----
    scores_kernel<<<(E_lbl + 15) / 16, 256, 0, stream>>>(xp, xg, e_lbl, E_lbl, (float*)d_out);
}

// Round 3
// 1448.750 us; speedup vs baseline: 1.4136x; 1.2126x over previous
//
#include <hip/hip_runtime.h>
#include <hip/hip_bf16.h>
#include <math.h>

#define H 128

// ---------------- CSR build ----------------
// Counts for all 3 edge types live in ONE concatenated buffer [NP(isa) | NG(rel) | NP(rev)].
// One hierarchical scan produces GLOBAL offsets -> one shared col buffer, rowptr slices per type.

__global__ __launch_bounds__(256) void count_kernel(const int* __restrict__ edges, int E,
                                                    int* __restrict__ cnt) {
    int e = blockIdx.x * 256 + threadIdx.x;
    if (e < E) atomicAdd(&cnt[edges[E + e]], 1);
}

// pass1: per-block (1024 elems) sums
__global__ __launch_bounds__(256) void scan_pass1(const int* __restrict__ cnt, int n,
                                                  int* __restrict__ partial) {
    int base = blockIdx.x * 1024 + threadIdx.x * 4;
    int s = 0;
    if (base + 3 < n) {
        int4 v = *(const int4*)&cnt[base];
        s = v.x + v.y + v.z + v.w;
    } else {
        for (int i = 0; i < 4; ++i) if (base + i < n) s += cnt[base + i];
    }
    __shared__ int red[256];
    red[threadIdx.x] = s;
    __syncthreads();
    for (int off = 128; off; off >>= 1) {
        if (threadIdx.x < off) red[threadIdx.x] += red[threadIdx.x + off];
        __syncthreads();
    }
    if (threadIdx.x == 0) partial[blockIdx.x] = red[0];
}

// pass2: single block exclusive-scans the partials (nb <= 1024)
__global__ __launch_bounds__(1024) void scan_pass2(int* __restrict__ partial, int nb,
                                                   int* __restrict__ total_out) {
    __shared__ int sh[1024];
    int t = threadIdx.x;
    int v = (t < nb) ? partial[t] : 0;
    sh[t] = v;
    __syncthreads();
    for (int off = 1; off < 1024; off <<= 1) {
        int u = (t >= off) ? sh[t - off] : 0;
        __syncthreads();
        sh[t] += u;
        __syncthreads();
    }
    if (t < nb) partial[t] = sh[t] - v;   // exclusive
    if (t == 1023) *total_out = sh[1023];
}

// pass3: per-block local exclusive scan + block offset; writes rowptr and cursor
__global__ __launch_bounds__(256) void scan_pass3(const int* __restrict__ cnt, int n,
                                                  const int* __restrict__ partial,
                                                  int* __restrict__ rowptr,
                                                  int* __restrict__ cursor) {
    int t = threadIdx.x;
    int base = blockIdx.x * 1024 + t * 4;
    int v[4];
    int s = 0;
    for (int i = 0; i < 4; ++i) {
        v[i] = (base + i < n) ? cnt[base + i] : 0;
        s += v[i];
    }
    __shared__ int sh[256];
    sh[t] = s;
    __syncthreads();
    for (int off = 1; off < 256; off <<= 1) {
        int u = (t >= off) ? sh[t - off] : 0;
        __syncthreads();
        sh[t] += u;
        __syncthreads();
    }
    int run = partial[blockIdx.x] + sh[t] - s;
    for (int i = 0; i < 4; ++i) {
        int idx = base + i;
        if (idx < n) {
            rowptr[idx] = run;
            cursor[idx] = run;
            run += v[i];
        }
    }
}

__global__ __launch_bounds__(256) void fill_kernel(const int* __restrict__ edges, int E,
                                                   int* __restrict__ cursor, int* __restrict__ col) {
    int e = blockIdx.x * 256 + threadIdx.x;
    if (e < E) {
        int src = edges[e];
        int dst = edges[E + e];
        col[atomicAdd(&cursor[dst], 1)] = src;
    }
}

// ---------------- Wsum = Wr_isa + Wr_rev (all 3 layers), float4 ----------------

__global__ __launch_bounds__(256) void add_w_kernel(const float* __restrict__ a,
                                                    const float* __restrict__ b,
                                                    float* __restrict__ o, int n4) {
    int i = blockIdx.x * 256 + threadIdx.x;
    if (i < n4) {
        float4 x = ((const float4*)a)[i];
        float4 y = ((const float4*)b)[i];
        x.x += y.x; x.y += y.y; x.z += y.z; x.w += y.w;
        ((float4*)o)[i] = x;
    }
}

// ---------------- segment mean (gather over CSR) ----------------
// one wave per dst node; lane covers 2 channels (float2).
// 4-way edge unroll: 4 independent 512B row-gathers in flight per wave (latency hiding).

__global__ __launch_bounds__(256) void agg_mean_kernel(const float* __restrict__ x,
                                                       const int* __restrict__ rowptr,
                                                       const int* __restrict__ col,
                                                       float* __restrict__ out, int n_dst) {
    int w = (blockIdx.x << 2) + (threadIdx.x >> 6);
    int lane = threadIdx.x & 63;
    if (w >= n_dst) return;
    int beg = rowptr[w], end = rowptr[w + 1];
    int off = lane * 2;
    float ax0 = 0.f, ay0 = 0.f, ax1 = 0.f, ay1 = 0.f;
    float ax2 = 0.f, ay2 = 0.f, ax3 = 0.f, ay3 = 0.f;
    int e = beg;
    for (; e + 3 < end; e += 4) {
        int s0 = col[e], s1 = col[e + 1], s2 = col[e + 2], s3 = col[e + 3];
        float2 v0 = *(const float2*)&x[(size_t)s0 * H + off];
        float2 v1 = *(const float2*)&x[(size_t)s1 * H + off];
        float2 v2 = *(const float2*)&x[(size_t)s2 * H + off];
        float2 v3 = *(const float2*)&x[(size_t)s3 * H + off];
        ax0 += v0.x; ay0 += v0.y;
        ax1 += v1.x; ay1 += v1.y;
        ax2 += v2.x; ay2 += v2.y;
        ax3 += v3.x; ay3 += v3.y;
    }
    for (; e < end; ++e) {
        int s = col[e];
        float2 v = *(const float2*)&x[(size_t)s * H + off];
        ax0 += v.x; ay0 += v.y;
    }
    float ax = (ax0 + ax1) + (ax2 + ax3);
    float ay = (ay0 + ay1) + (ay2 + ay3);
    int c = end - beg; if (c < 1) c = 1;
    float inv = 1.0f / (float)c;
    float2 r; r.x = ax * inv; r.y = ay * inv;
    *(float2*)&out[(size_t)w * H + off] = r;
}

// ---------------- fused multi-input GEMM ----------------
// out[r,:] = sum_m A_m[r,:] @ W_m + b0 + b1, optional leaky relu.
// Block: 32 rows x 128 cols (grid ~1563 -> 6.1 blocks/CU vs 3.05 with 64-row tiles).
// Thread: 4 rows x 4 cols. LDS 16KB. Wave spans 2 row-groups -> 2-addr LDS broadcast (free).
// In-place safe when out == A_m: block stages (reads) only its own 32 rows, writes at end.

__device__ __forceinline__ void fma4(float4& acc, float s, const float4& w) {
    acc.x = fmaf(s, w.x, acc.x);
    acc.y = fmaf(s, w.y, acc.y);
    acc.z = fmaf(s, w.z, acc.z);
    acc.w = fmaf(s, w.w, acc.w);
}

template <int NIN>
__global__ __launch_bounds__(256) void gemm_fused(
    const float* __restrict__ A0, const float* __restrict__ A1, const float* __restrict__ A2,
    const float* __restrict__ W0, const float* __restrict__ W1, const float* __restrict__ W2,
    const float* __restrict__ b0, const float* __restrict__ b1,
    float* __restrict__ out, int n_rows, int relu) {
    __shared__ float As[32 * H];
    const int tid = threadIdx.x;
    const int r0 = blockIdx.x * 32;
    const int cg = (tid & 31) * 4;   // col start (0..124)
    const int rg = (tid >> 5) * 4;   // row start within block (0..28)

    float4 bias = *(const float4*)&b0[cg];
    if (b1) {
        float4 t = *(const float4*)&b1[cg];
        bias.x += t.x; bias.y += t.y; bias.z += t.z; bias.w += t.w;
    }
    float4 acc[4];
#pragma unroll
    for (int r = 0; r < 4; ++r) acc[r] = bias;

    const float* Aarr[3] = {A0, A1, A2};
    const float* Warr[3] = {W0, W1, W2};

    for (int m = 0; m < NIN; ++m) {
        const float* __restrict__ A = Aarr[m];
        __syncthreads();
#pragma unroll
        for (int i = 0; i < 4; ++i) {
            int f = tid + i * 256;          // float4 index 0..1023
            int row = f >> 5;               // 32 float4 per row
            int cc = (f & 31) * 4;
            int gr = r0 + row;
            if (gr >= n_rows) gr = n_rows - 1;
            *(float4*)&As[row * H + cc] = *(const float4*)&A[(size_t)gr * H + cc];
        }
        __syncthreads();
        const float* __restrict__ W = Warr[m];
        for (int k = 0; k < H; k += 4) {
            float4 w0 = *(const float4*)&W[(k + 0) * H + cg];
            float4 w1 = *(const float4*)&W[(k + 1) * H + cg];
            float4 w2 = *(const float4*)&W[(k + 2) * H + cg];
            float4 w3 = *(const float4*)&W[(k + 3) * H + cg];
#pragma unroll
            for (int r = 0; r < 4; ++r) {
                float4 a = *(const float4*)&As[(rg + r) * H + k];
                fma4(acc[r], a.x, w0);
                fma4(acc[r], a.y, w1);
                fma4(acc[r], a.z, w2);
                fma4(acc[r], a.w, w3);
            }
        }
    }

#pragma unroll
    for (int r = 0; r < 4; ++r) {
        int gr = r0 + rg + r;
        if (gr < n_rows) {
            float4 v = acc[r];
            if (relu) {
                v.x = v.x > 0.f ? v.x : 0.01f * v.x;
                v.y = v.y > 0.f ? v.y : 0.01f * v.y;
                v.z = v.z > 0.f ? v.z : 0.01f * v.z;
                v.w = v.w > 0.f ? v.w : 0.01f * v.w;
            }
            *(float4*)&out[(size_t)gr * H + cg] = v;
        }
    }
}

// ---------------- edge decoder: sigmoid(dot(xp[i], xg[j])) ----------------

__global__ __launch_bounds__(256) void scores_kernel(const float* __restrict__ xp,
                                                     const float* __restrict__ xg,
                                                     const int* __restrict__ eli, int E,
                                                     float* __restrict__ out) {
    int lane16 = threadIdx.x & 15;
    int sub = threadIdx.x >> 4;     // 16 edges per block
    int e = blockIdx.x * 16 + sub;
    if (e >= E) return;
    int ip = eli[e];
    int ig = eli[E + e];
    const float4* p = (const float4*)&xp[(size_t)ip * H];
    const float4* g = (const float4*)&xg[(size_t)ig * H];
    float4 a0 = p[lane16], a1 = p[lane16 + 16];
    float4 b0 = g[lane16], b1 = g[lane16 + 16];
    float s = a0.x * b0.x + a0.y * b0.y + a0.z * b0.z + a0.w * b0.w
            + a1.x * b1.x + a1.y * b1.y + a1.z * b1.z + a1.w * b1.w;
#pragma unroll
    for (int off = 8; off; off >>= 1) s += __shfl_xor(s, off, 16);
    if (lane16 == 0) out[e] = 1.0f / (1.0f + expf(-s));
}

// ---------------- host ----------------

extern "C" void kernel_launch(void* const* d_in, const int* in_sizes, int n_in,
                              void* d_out, int out_size, void* d_ws, size_t ws_size,
                              hipStream_t stream) {
    const float* x_pheno = (const float*)d_in[0];
    const float* x_gene  = (const float*)d_in[1];
    const float* Wl_isa  = (const float*)d_in[2];
    const float* bl_isa  = (const float*)d_in[3];
    const float* Wr_isa  = (const float*)d_in[4];
    const float* Wl_rel  = (const float*)d_in[5];
    const float* bl_rel  = (const float*)d_in[6];
    const float* Wr_rel  = (const float*)d_in[7];
    const float* Wl_rev  = (const float*)d_in[8];
    const float* bl_rev  = (const float*)d_in[9];
    const float* Wr_rev  = (const float*)d_in[10];
    const int* e_isa = (const int*)d_in[11];
    const int* e_rel = (const int*)d_in[12];
    const int* e_rev = (const int*)d_in[13];
    const int* e_lbl = (const int*)d_in[14];
    const int E_isa = in_sizes[11] / 2;
    const int E_rel = in_sizes[12] / 2;
    const int E_rev = in_sizes[13] / 2;
    const int E_lbl = in_sizes[14] / 2;
    const int NP = in_sizes[0] / H;
    const int NG = in_sizes[1] / H;
    const int NMAX = NP > NG ? NP : NG;
    const int n_tot = NP + NG + NP;            // concatenated count/rowptr space
    const int E_tot = E_isa + E_rel + E_rev;
    const int nb = (n_tot + 1023) / 1024;      // scan blocks (<=1024)

    char* ws = (char*)d_ws;
    auto alloc = [&](size_t bytes) -> char* {
        char* p = ws;
        ws += (bytes + 255) & ~(size_t)255;
        return p;
    };
    float* B[5];
    for (int i = 0; i < 5; ++i) B[i] = (float*)alloc((size_t)NMAX * H * sizeof(float));
    int* cnt    = (int*)alloc((size_t)n_tot * 4);        // counts, then consumed by scan
    int* rowptr = (int*)alloc((size_t)(n_tot + 1) * 4);  // global exclusive offsets
    int* cursor = (int*)alloc((size_t)n_tot * 4);        // mutable copy for fill
    int* col    = (int*)alloc((size_t)E_tot * 4);        // shared column buffer
    int* partial = (int*)alloc((size_t)1024 * 4);
    float* Wsum = (float*)alloc((size_t)3 * H * H * sizeof(float));  // Wr_isa + Wr_rev

    int* cnt_isa = cnt;             // dst in [0,NP)
    int* cnt_rel = cnt + NP;        // dst in [0,NG)
    int* cnt_rev = cnt + NP + NG;   // dst in [0,NP)
    const int* rp_isa = rowptr;
    const int* rp_rel = rowptr + NP;
    const int* rp_rev = rowptr + NP + NG;

    // ---- CSR build (every call; ws is re-poisoned by the harness) ----
    hipMemsetAsync(cnt, 0, (size_t)n_tot * 4, stream);
    count_kernel<<<(E_isa + 255) / 256, 256, 0, stream>>>(e_isa, E_isa, cnt_isa);
    count_kernel<<<(E_rel + 255) / 256, 256, 0, stream>>>(e_rel, E_rel, cnt_rel);
    count_kernel<<<(E_rev + 255) / 256, 256, 0, stream>>>(e_rev, E_rev, cnt_rev);
    scan_pass1<<<nb, 256, 0, stream>>>(cnt, n_tot, partial);
    scan_pass2<<<1, 1024, 0, stream>>>(partial, nb, &rowptr[n_tot]);
    scan_pass3<<<nb, 256, 0, stream>>>(cnt, n_tot, partial, rowptr, cursor);
    fill_kernel<<<(E_isa + 255) / 256, 256, 0, stream>>>(e_isa, E_isa, cursor, col);
    fill_kernel<<<(E_rel + 255) / 256, 256, 0, stream>>>(e_rel, E_rel, cursor + NP, col);
    fill_kernel<<<(E_rev + 255) / 256, 256, 0, stream>>>(e_rev, E_rev, cursor + NP + NG, col);

    // ---- Wsum precompute ----
    add_w_kernel<<<(3 * H * H / 4 + 255) / 256, 256, 0, stream>>>(Wr_isa, Wr_rev, Wsum, 3 * H * H / 4);

    // ---- 3 layers ----
    // buffers: layer0 M1=B0 M2=B1 M3=B2; layer1 M1=B3 M2=B1 M3=B4; layer2 M1=B0 M2=B1 M3=B2
    int mi[3] = {0, 3, 0}, mv[3] = {1, 1, 1}, mr[3] = {2, 4, 2};
    const float* xp = x_pheno;
    const float* xg = x_gene;
    for (int l = 0; l < 3; ++l) {
        float* M1 = B[mi[l]];
        float* M2 = B[mv[l]];
        float* M3 = B[mr[l]];
        agg_mean_kernel<<<(NP + 3) / 4, 256, 0, stream>>>(xp, rp_isa, col, M1, NP);
        agg_mean_kernel<<<(NP + 3) / 4, 256, 0, stream>>>(xg, rp_rev, col, M2, NP);
        agg_mean_kernel<<<(NG + 3) / 4, 256, 0, stream>>>(xp, rp_rel, col, M3, NG);
        int relu = (l < 2) ? 1 : 0;
        const float* Wli = Wl_isa + (size_t)l * H * H;
        const float* bli = bl_isa + (size_t)l * H;
        const float* Wlv = Wl_rev + (size_t)l * H * H;
        const float* blv = bl_rev + (size_t)l * H;
        const float* Wlr = Wl_rel + (size_t)l * H * H;
        const float* blr = bl_rel + (size_t)l * H;
        const float* Wrr = Wr_rel + (size_t)l * H * H;
        const float* Wsl = Wsum + (size_t)l * H * H;
        // new_p = M1@Wl_isa + M2@Wl_rev + xp@(Wr_isa+Wr_rev) + bl_isa + bl_rev -> M1 (in-place)
        gemm_fused<3><<<(NP + 31) / 32, 256, 0, stream>>>(
            M1, M2, xp, Wli, Wlv, Wsl, bli, blv, M1, NP, relu);
        // new_g = M3@Wl_rel + xg@Wr_rel + bl_rel -> M3 (in-place)
        gemm_fused<2><<<(NG + 31) / 32, 256, 0, stream>>>(
            M3, xg, nullptr, Wlr, Wrr, nullptr, blr, nullptr, M3, NG, relu);
        xp = M1;
        xg = M3;
    }

    // ---- decoder ----
    scores_kernel<<<(E_lbl + 15) / 16, 256, 0, stream>>>(xp, xg, e_lbl, E_lbl, (float*)d_out);
}

// Round 4
// 1409.202 us; speedup vs baseline: 1.4533x; 1.0281x over previous
//
#include <hip/hip_runtime.h>
#include <hip/hip_bf16.h>
#include <math.h>

#define H 128
#define RS 136  // LDS row stride in shorts (128 + 8 pad -> even bank spread for b128 reads)

typedef __attribute__((ext_vector_type(8))) short short8;
typedef __attribute__((ext_vector_type(4))) short short4v;
typedef __attribute__((ext_vector_type(4))) float f32x4;

// fp32 -> bf16 (RNE) and back; values here are finite (no NaN handling needed)
__device__ __forceinline__ short f2bf(float f) {
    unsigned u = __float_as_uint(f);
    u += 0x7fff + ((u >> 16) & 1);
    return (short)(u >> 16);
}
__device__ __forceinline__ float bf2f(short h) {
    return __uint_as_float(((unsigned)(unsigned short)h) << 16);
}

// ---------------- CSR build ----------------
// Counts for all 3 edge types in ONE concatenated buffer [NP(isa) | NG(rel) | NP(rev)].

__global__ __launch_bounds__(256) void count_kernel(const int* __restrict__ edges, int E,
                                                    int* __restrict__ cnt) {
    int e = blockIdx.x * 256 + threadIdx.x;
    if (e < E) atomicAdd(&cnt[edges[E + e]], 1);
}

__global__ __launch_bounds__(256) void scan_pass1(const int* __restrict__ cnt, int n,
                                                  int* __restrict__ partial) {
    int base = blockIdx.x * 1024 + threadIdx.x * 4;
    int s = 0;
    if (base + 3 < n) {
        int4 v = *(const int4*)&cnt[base];
        s = v.x + v.y + v.z + v.w;
    } else {
        for (int i = 0; i < 4; ++i) if (base + i < n) s += cnt[base + i];
    }
    __shared__ int red[256];
    red[threadIdx.x] = s;
    __syncthreads();
    for (int off = 128; off; off >>= 1) {
        if (threadIdx.x < off) red[threadIdx.x] += red[threadIdx.x + off];
        __syncthreads();
    }
    if (threadIdx.x == 0) partial[blockIdx.x] = red[0];
}

__global__ __launch_bounds__(1024) void scan_pass2(int* __restrict__ partial, int nb,
                                                   int* __restrict__ total_out) {
    __shared__ int sh[1024];
    int t = threadIdx.x;
    int v = (t < nb) ? partial[t] : 0;
    sh[t] = v;
    __syncthreads();
    for (int off = 1; off < 1024; off <<= 1) {
        int u = (t >= off) ? sh[t - off] : 0;
        __syncthreads();
        sh[t] += u;
        __syncthreads();
    }
    if (t < nb) partial[t] = sh[t] - v;   // exclusive
    if (t == 1023) *total_out = sh[1023];
}

__global__ __launch_bounds__(256) void scan_pass3(const int* __restrict__ cnt, int n,
                                                  const int* __restrict__ partial,
                                                  int* __restrict__ rowptr,
                                                  int* __restrict__ cursor) {
    int t = threadIdx.x;
    int base = blockIdx.x * 1024 + t * 4;
    int v[4];
    int s = 0;
    for (int i = 0; i < 4; ++i) {
        v[i] = (base + i < n) ? cnt[base + i] : 0;
        s += v[i];
    }
    __shared__ int sh[256];
    sh[t] = s;
    __syncthreads();
    for (int off = 1; off < 256; off <<= 1) {
        int u = (t >= off) ? sh[t - off] : 0;
        __syncthreads();
        sh[t] += u;
        __syncthreads();
    }
    int run = partial[blockIdx.x] + sh[t] - s;
    for (int i = 0; i < 4; ++i) {
        int idx = base + i;
        if (idx < n) {
            rowptr[idx] = run;
            cursor[idx] = run;
            run += v[i];
        }
    }
}

__global__ __launch_bounds__(256) void fill_kernel(const int* __restrict__ edges, int E,
                                                   int* __restrict__ cursor, int* __restrict__ col) {
    int e = blockIdx.x * 256 + threadIdx.x;
    if (e < E) {
        int src = edges[e];
        int dst = edges[E + e];
        col[atomicAdd(&cursor[dst], 1)] = src;
    }
}

// ---------------- W pack: fp32 [k][n] -> MFMA B-fragment order, split bf16 hi/lo ----------------
// 15 matrices (5 per layer: Wl_isa, Wl_rev, Wsum=Wr_isa+Wr_rev, Wl_rel, Wr_rel).
// Fragment order: [mat][kc][ct][lane][j]  (j=0..7), so a wave's b-frag = one coalesced 16B load.
// B-operand layout: n = ct*16 + (lane&15), k = kc*32 + (lane>>4)*8 + j.

struct WSrc { const float* a[15]; const float* b[15]; };

__global__ __launch_bounds__(256) void pack_w_kernel(WSrc src, short* __restrict__ whi,
                                                     short* __restrict__ wlo) {
    int idx = blockIdx.x * 256 + threadIdx.x;   // (mat, kc, ct, lane)
    if (idx >= 15 * 4 * 8 * 64) return;
    int lane = idx & 63;
    int ct = (idx >> 6) & 7;
    int kc = (idx >> 9) & 3;
    int mat = idx >> 11;
    const float* A = src.a[mat];
    const float* Bp = src.b[mat];
    int n = ct * 16 + (lane & 15);
    int kbase = kc * 32 + (lane >> 4) * 8;
    size_t o = (size_t)idx * 8;
    for (int j = 0; j < 8; ++j) {
        float v = A[(size_t)(kbase + j) * H + n];
        if (Bp) v += Bp[(size_t)(kbase + j) * H + n];
        short h = f2bf(v);
        short lo = f2bf(v - bf2f(h));
        whi[o + j] = h;
        wlo[o + j] = lo;
    }
}

// ---------------- segment mean (gather over CSR), 4-way edge unroll ----------------

__global__ __launch_bounds__(256) void agg_mean_kernel(const float* __restrict__ x,
                                                       const int* __restrict__ rowptr,
                                                       const int* __restrict__ col,
                                                       float* __restrict__ out, int n_dst) {
    int w = (blockIdx.x << 2) + (threadIdx.x >> 6);
    int lane = threadIdx.x & 63;
    if (w >= n_dst) return;
    int beg = rowptr[w], end = rowptr[w + 1];
    int off = lane * 2;
    float ax0 = 0.f, ay0 = 0.f, ax1 = 0.f, ay1 = 0.f;
    float ax2 = 0.f, ay2 = 0.f, ax3 = 0.f, ay3 = 0.f;
    int e = beg;
    for (; e + 3 < end; e += 4) {
        int s0 = col[e], s1 = col[e + 1], s2 = col[e + 2], s3 = col[e + 3];
        float2 v0 = *(const float2*)&x[(size_t)s0 * H + off];
        float2 v1 = *(const float2*)&x[(size_t)s1 * H + off];
        float2 v2 = *(const float2*)&x[(size_t)s2 * H + off];
        float2 v3 = *(const float2*)&x[(size_t)s3 * H + off];
        ax0 += v0.x; ay0 += v0.y;
        ax1 += v1.x; ay1 += v1.y;
        ax2 += v2.x; ay2 += v2.y;
        ax3 += v3.x; ay3 += v3.y;
    }
    for (; e < end; ++e) {
        int s = col[e];
        float2 v = *(const float2*)&x[(size_t)s * H + off];
        ax0 += v.x; ay0 += v.y;
    }
    float ax = (ax0 + ax1) + (ax2 + ax3);
    float ay = (ay0 + ay1) + (ay2 + ay3);
    int c = end - beg; if (c < 1) c = 1;
    float inv = 1.0f / (float)c;
    float2 r; r.x = ax * inv; r.y = ay * inv;
    *(float2*)&out[(size_t)w * H + off] = r;
}

// ---------------- split-bf16 MFMA GEMM ----------------
// out[r,:] = sum_m A_m[r,:] @ W_m + b0 (+ b1), optional leaky relu.
// fp32 emulated as 3 bf16 MFMAs: a_hi*w_hi + a_lo*w_hi + a_hi*w_lo (err ~2^-16 rel).
// Block: 64 rows x 128 cols, 4 waves; wave = 16-row strip x 8 col-tiles of 16x16x32.
// A staged in LDS as bf16 hi/lo, row stride RS=136 shorts (pad -> even bank spread).
// In-place safe when out == A_m: block stages (reads) only its own 64 rows, writes at end.

template <int NIN>
__global__ __launch_bounds__(256) void gemm_mfma(
    const float* __restrict__ A0, const float* __restrict__ A1, const float* __restrict__ A2,
    const short* __restrict__ whi, const short* __restrict__ wlo,
    int mat0, int mat1, int mat2,
    const float* __restrict__ b0, const float* __restrict__ b1,
    float* __restrict__ out, int n_rows, int relu) {
    __shared__ short Ahi[64 * RS];
    __shared__ short Alo[64 * RS];
    const int tid = threadIdx.x;
    const int lane = tid & 63;
    const int wave = tid >> 6;
    const int r0 = blockIdx.x * 64;

    f32x4 acc[8];
#pragma unroll
    for (int ct = 0; ct < 8; ++ct) acc[ct] = (f32x4){0.f, 0.f, 0.f, 0.f};

    const float* Aarr[3] = {A0, A1, A2};
    const int marr[3] = {mat0, mat1, mat2};

    // A-operand fragment position: m = lane&15 (row in strip), k = (lane>>4)*8 + j
    const int arow = wave * 16 + (lane & 15);
    const int acol = (lane >> 4) * 8;

    for (int m = 0; m < NIN; ++m) {
        const float* __restrict__ A = Aarr[m];
        __syncthreads();   // protect LDS from previous m's readers
#pragma unroll
        for (int i = 0; i < 8; ++i) {
            int f = tid + i * 256;        // float4 unit 0..2047
            int row = f >> 5;             // 32 float4 per row
            int c4 = (f & 31) * 4;
            int gr = r0 + row;
            if (gr >= n_rows) gr = n_rows - 1;
            float4 v = *(const float4*)&A[(size_t)gr * H + c4];
            short h0 = f2bf(v.x), h1 = f2bf(v.y), h2 = f2bf(v.z), h3 = f2bf(v.w);
            short l0 = f2bf(v.x - bf2f(h0)), l1 = f2bf(v.y - bf2f(h1));
            short l2 = f2bf(v.z - bf2f(h2)), l3 = f2bf(v.w - bf2f(h3));
            *(short4v*)&Ahi[row * RS + c4] = (short4v){h0, h1, h2, h3};
            *(short4v*)&Alo[row * RS + c4] = (short4v){l0, l1, l2, l3};
        }
        __syncthreads();
        const short* __restrict__ wh = whi + (size_t)marr[m] * (32 * 64 * 8);
        const short* __restrict__ wl = wlo + (size_t)marr[m] * (32 * 64 * 8);
#pragma unroll
        for (int kc = 0; kc < 4; ++kc) {
            short8 ah = *(const short8*)&Ahi[arow * RS + kc * 32 + acol];
            short8 al = *(const short8*)&Alo[arow * RS + kc * 32 + acol];
#pragma unroll
            for (int ct = 0; ct < 8; ++ct) {
                size_t fo = ((size_t)(kc * 8 + ct) * 64 + lane) * 8;
                short8 bh = *(const short8*)&wh[fo];
                short8 bl = *(const short8*)&wl[fo];
                acc[ct] = __builtin_amdgcn_mfma_f32_16x16x32_bf16(ah, bh, acc[ct], 0, 0, 0);
                acc[ct] = __builtin_amdgcn_mfma_f32_16x16x32_bf16(al, bh, acc[ct], 0, 0, 0);
                acc[ct] = __builtin_amdgcn_mfma_f32_16x16x32_bf16(ah, bl, acc[ct], 0, 0, 0);
            }
        }
    }

    // epilogue: C/D layout col = lane&15, row = (lane>>4)*4 + reg
    const int orow = r0 + wave * 16 + (lane >> 4) * 4;
    const int ncol = lane & 15;
#pragma unroll
    for (int ct = 0; ct < 8; ++ct) {
        int n = ct * 16 + ncol;
        float bs = b0[n];
        if (b1) bs += b1[n];
#pragma unroll
        for (int reg = 0; reg < 4; ++reg) {
            int gr = orow + reg;
            if (gr < n_rows) {
                float v = acc[ct][reg] + bs;
                if (relu) v = v > 0.f ? v : 0.01f * v;
                out[(size_t)gr * H + n] = v;
            }
        }
    }
}

// ---------------- edge decoder: sigmoid(dot(xp[i], xg[j])) ----------------

__global__ __launch_bounds__(256) void scores_kernel(const float* __restrict__ xp,
                                                     const float* __restrict__ xg,
                                                     const int* __restrict__ eli, int E,
                                                     float* __restrict__ out) {
    int lane16 = threadIdx.x & 15;
    int sub = threadIdx.x >> 4;     // 16 edges per block
    int e = blockIdx.x * 16 + sub;
    if (e >= E) return;
    int ip = eli[e];
    int ig = eli[E + e];
    const float4* p = (const float4*)&xp[(size_t)ip * H];
    const float4* g = (const float4*)&xg[(size_t)ig * H];
    float4 a0 = p[lane16], a1 = p[lane16 + 16];
    float4 b0 = g[lane16], b1 = g[lane16 + 16];
    float s = a0.x * b0.x + a0.y * b0.y + a0.z * b0.z + a0.w * b0.w
            + a1.x * b1.x + a1.y * b1.y + a1.z * b1.z + a1.w * b1.w;
#pragma unroll
    for (int off = 8; off; off >>= 1) s += __shfl_xor(s, off, 16);
    if (lane16 == 0) out[e] = 1.0f / (1.0f + expf(-s));
}

// ---------------- host ----------------

extern "C" void kernel_launch(void* const* d_in, const int* in_sizes, int n_in,
                              void* d_out, int out_size, void* d_ws, size_t ws_size,
                              hipStream_t stream) {
    const float* x_pheno = (const float*)d_in[0];
    const float* x_gene  = (const float*)d_in[1];
    const float* Wl_isa  = (const float*)d_in[2];
    const float* bl_isa  = (const float*)d_in[3];
    const float* Wr_isa  = (const float*)d_in[4];
    const float* Wl_rel  = (const float*)d_in[5];
    const float* bl_rel  = (const float*)d_in[6];
    const float* Wr_rel  = (const float*)d_in[7];
    const float* Wl_rev  = (const float*)d_in[8];
    const float* bl_rev  = (const float*)d_in[9];
    const float* Wr_rev  = (const float*)d_in[10];
    const int* e_isa = (const int*)d_in[11];
    const int* e_rel = (const int*)d_in[12];
    const int* e_rev = (const int*)d_in[13];
    const int* e_lbl = (const int*)d_in[14];
    const int E_isa = in_sizes[11] / 2;
    const int E_rel = in_sizes[12] / 2;
    const int E_rev = in_sizes[13] / 2;
    const int E_lbl = in_sizes[14] / 2;
    const int NP = in_sizes[0] / H;
    const int NG = in_sizes[1] / H;
    const int NMAX = NP > NG ? NP : NG;
    const int n_tot = NP + NG + NP;
    const int E_tot = E_isa + E_rel + E_rev;
    const int nb = (n_tot + 1023) / 1024;

    char* ws = (char*)d_ws;
    auto alloc = [&](size_t bytes) -> char* {
        char* p = ws;
        ws += (bytes + 255) & ~(size_t)255;
        return p;
    };
    float* B[5];
    for (int i = 0; i < 5; ++i) B[i] = (float*)alloc((size_t)NMAX * H * sizeof(float));
    int* cnt    = (int*)alloc((size_t)n_tot * 4);
    int* rowptr = (int*)alloc((size_t)(n_tot + 1) * 4);
    int* cursor = (int*)alloc((size_t)n_tot * 4);
    int* col    = (int*)alloc((size_t)E_tot * 4);
    int* partial = (int*)alloc((size_t)1024 * 4);
    short* whi = (short*)alloc((size_t)15 * H * H * sizeof(short));  // packed bf16-hi W frags
    short* wlo = (short*)alloc((size_t)15 * H * H * sizeof(short));  // packed bf16-lo W frags

    int* cnt_isa = cnt;             // dst in [0,NP)
    int* cnt_rel = cnt + NP;        // dst in [0,NG)
    int* cnt_rev = cnt + NP + NG;   // dst in [0,NP)
    const int* rp_isa = rowptr;
    const int* rp_rel = rowptr + NP;
    const int* rp_rev = rowptr + NP + NG;

    // ---- CSR build (every call; ws is re-poisoned by the harness) ----
    hipMemsetAsync(cnt, 0, (size_t)n_tot * 4, stream);
    count_kernel<<<(E_isa + 255) / 256, 256, 0, stream>>>(e_isa, E_isa, cnt_isa);
    count_kernel<<<(E_rel + 255) / 256, 256, 0, stream>>>(e_rel, E_rel, cnt_rel);
    count_kernel<<<(E_rev + 255) / 256, 256, 0, stream>>>(e_rev, E_rev, cnt_rev);
    scan_pass1<<<nb, 256, 0, stream>>>(cnt, n_tot, partial);
    scan_pass2<<<1, 1024, 0, stream>>>(partial, nb, &rowptr[n_tot]);
    scan_pass3<<<nb, 256, 0, stream>>>(cnt, n_tot, partial, rowptr, cursor);
    fill_kernel<<<(E_isa + 255) / 256, 256, 0, stream>>>(e_isa, E_isa, cursor, col);
    fill_kernel<<<(E_rel + 255) / 256, 256, 0, stream>>>(e_rel, E_rel, cursor + NP, col);
    fill_kernel<<<(E_rev + 255) / 256, 256, 0, stream>>>(e_rev, E_rev, cursor + NP + NG, col);

    // ---- W pack: per layer slots {Wl_isa, Wl_rev, Wsum=Wr_isa+Wr_rev, Wl_rel, Wr_rel} ----
    WSrc src;
    for (int l = 0; l < 3; ++l) {
        src.a[l * 5 + 0] = Wl_isa + (size_t)l * H * H;  src.b[l * 5 + 0] = nullptr;
        src.a[l * 5 + 1] = Wl_rev + (size_t)l * H * H;  src.b[l * 5 + 1] = nullptr;
        src.a[l * 5 + 2] = Wr_isa + (size_t)l * H * H;  src.b[l * 5 + 2] = Wr_rev + (size_t)l * H * H;
        src.a[l * 5 + 3] = Wl_rel + (size_t)l * H * H;  src.b[l * 5 + 3] = nullptr;
        src.a[l * 5 + 4] = Wr_rel + (size_t)l * H * H;  src.b[l * 5 + 4] = nullptr;
    }
    pack_w_kernel<<<(15 * 4 * 8 * 64 + 255) / 256, 256, 0, stream>>>(src, whi, wlo);

    // ---- 3 layers ----
    // buffers: layer0 M1=B0 M2=B1 M3=B2; layer1 M1=B3 M2=B1 M3=B4; layer2 M1=B0 M2=B1 M3=B2
    int mi[3] = {0, 3, 0}, mv[3] = {1, 1, 1}, mr[3] = {2, 4, 2};
    const float* xp = x_pheno;
    const float* xg = x_gene;
    for (int l = 0; l < 3; ++l) {
        float* M1 = B[mi[l]];
        float* M2 = B[mv[l]];
        float* M3 = B[mr[l]];
        agg_mean_kernel<<<(NP + 3) / 4, 256, 0, stream>>>(xp, rp_isa, col, M1, NP);
        agg_mean_kernel<<<(NP + 3) / 4, 256, 0, stream>>>(xg, rp_rev, col, M2, NP);
        agg_mean_kernel<<<(NG + 3) / 4, 256, 0, stream>>>(xp, rp_rel, col, M3, NG);
        int relu = (l < 2) ? 1 : 0;
        const float* bli = bl_isa + (size_t)l * H;
        const float* blv = bl_rev + (size_t)l * H;
        const float* blr = bl_rel + (size_t)l * H;
        // new_p = M1@Wl_isa + M2@Wl_rev + xp@(Wr_isa+Wr_rev) + bl_isa + bl_rev -> M1 (in-place)
        gemm_mfma<3><<<(NP + 63) / 64, 256, 0, stream>>>(
            M1, M2, xp, whi, wlo, l * 5 + 0, l * 5 + 1, l * 5 + 2, bli, blv, M1, NP, relu);
        // new_g = M3@Wl_rel + xg@Wr_rel + bl_rel -> M3 (in-place)
        gemm_mfma<2><<<(NG + 63) / 64, 256, 0, stream>>>(
            M3, xg, nullptr, whi, wlo, l * 5 + 3, l * 5 + 4, 0, blr, nullptr, M3, NG, relu);
        xp = M1;
        xg = M3;
    }

    // ---- decoder ----
    scores_kernel<<<(E_lbl + 15) / 16, 256, 0, stream>>>(xp, xg, e_lbl, E_lbl, (float*)d_out);
}

// Round 6
// 1141.745 us; speedup vs baseline: 1.7937x; 1.2343x over previous
//
#include <hip/hip_runtime.h>
#include <hip/hip_bf16.h>
#include <math.h>

#define H 128
#define RS 136  // LDS row stride in shorts (128 + 8 pad; keeps ds_read_b128 16B-aligned)

typedef __attribute__((ext_vector_type(8))) short short8;
typedef __attribute__((ext_vector_type(4))) short short4v;
typedef __attribute__((ext_vector_type(4))) float f32x4;

// fp32 -> bf16 (RNE); values here are finite (no NaN handling needed)
__device__ __forceinline__ short f2bf(float f) {
    unsigned u = __float_as_uint(f);
    u += 0x7fff + ((u >> 16) & 1);
    return (short)(u >> 16);
}
__device__ __forceinline__ float bf2f(short h) {
    return __uint_as_float(((unsigned)(unsigned short)h) << 16);
}

// ---------------- CSR build ----------------
// Counts for all 3 edge types in ONE concatenated buffer [NP(isa) | NG(rel) | NP(rev)].

__global__ __launch_bounds__(256) void count_kernel(const int* __restrict__ edges, int E,
                                                    int* __restrict__ cnt) {
    int e = blockIdx.x * 256 + threadIdx.x;
    if (e < E) atomicAdd(&cnt[edges[E + e]], 1);
}

__global__ __launch_bounds__(256) void scan_pass1(const int* __restrict__ cnt, int n,
                                                  int* __restrict__ partial) {
    int base = blockIdx.x * 1024 + threadIdx.x * 4;
    int s = 0;
    if (base + 3 < n) {
        int4 v = *(const int4*)&cnt[base];
        s = v.x + v.y + v.z + v.w;
    } else {
        for (int i = 0; i < 4; ++i) if (base + i < n) s += cnt[base + i];
    }
    __shared__ int red[256];
    red[threadIdx.x] = s;
    __syncthreads();
    for (int off = 128; off; off >>= 1) {
        if (threadIdx.x < off) red[threadIdx.x] += red[threadIdx.x + off];
        __syncthreads();
    }
    if (threadIdx.x == 0) partial[blockIdx.x] = red[0];
}

__global__ __launch_bounds__(1024) void scan_pass2(int* __restrict__ partial, int nb,
                                                   int* __restrict__ total_out) {
    __shared__ int sh[1024];
    int t = threadIdx.x;
    int v = (t < nb) ? partial[t] : 0;
    sh[t] = v;
    __syncthreads();
    for (int off = 1; off < 1024; off <<= 1) {
        int u = (t >= off) ? sh[t - off] : 0;
        __syncthreads();
        sh[t] += u;
        __syncthreads();
    }
    if (t < nb) partial[t] = sh[t] - v;   // exclusive
    if (t == 1023) *total_out = sh[1023];
}

__global__ __launch_bounds__(256) void scan_pass3(const int* __restrict__ cnt, int n,
                                                  const int* __restrict__ partial,
                                                  int* __restrict__ rowptr,
                                                  int* __restrict__ cursor) {
    int t = threadIdx.x;
    int base = blockIdx.x * 1024 + t * 4;
    int v[4];
    int s = 0;
    for (int i = 0; i < 4; ++i) {
        v[i] = (base + i < n) ? cnt[base + i] : 0;
        s += v[i];
    }
    __shared__ int sh[256];
    sh[t] = s;
    __syncthreads();
    for (int off = 1; off < 256; off <<= 1) {
        int u = (t >= off) ? sh[t - off] : 0;
        __syncthreads();
        sh[t] += u;
        __syncthreads();
    }
    int run = partial[blockIdx.x] + sh[t] - s;
    for (int i = 0; i < 4; ++i) {
        int idx = base + i;
        if (idx < n) {
            rowptr[idx] = run;
            cursor[idx] = run;
            run += v[i];
        }
    }
}

__global__ __launch_bounds__(256) void fill_kernel(const int* __restrict__ edges, int E,
                                                   int* __restrict__ cursor, int* __restrict__ col) {
    int e = blockIdx.x * 256 + threadIdx.x;
    if (e < E) {
        int src = edges[e];
        int dst = edges[E + e];
        col[atomicAdd(&cursor[dst], 1)] = src;
    }
}

// ---------------- W pack: fp32 [k][n] -> MFMA B-fragment order, split bf16 hi/lo ----------------
// 15 matrices (5 per layer: Wl_isa, Wl_rev, Wsum=Wr_isa+Wr_rev, Wl_rel, Wr_rel).
// Fragment order: [mat][kc][ct][lane][j] (j=0..7): a wave's (kc,ct) frag = 16B/lane coalesced.
// B-operand layout: n = ct*16 + (lane&15), k = kc*32 + (lane>>4)*8 + j.

struct WSrc { const float* a[15]; const float* b[15]; };

__global__ __launch_bounds__(256) void pack_w_kernel(WSrc src, short* __restrict__ whi,
                                                     short* __restrict__ wlo) {
    int idx = blockIdx.x * 256 + threadIdx.x;   // (mat, kc, ct, lane)
    if (idx >= 15 * 4 * 8 * 64) return;
    int lane = idx & 63;
    int ct = (idx >> 6) & 7;
    int kc = (idx >> 9) & 3;
    int mat = idx >> 11;
    const float* A = src.a[mat];
    const float* Bp = src.b[mat];
    int n = ct * 16 + (lane & 15);
    int kbase = kc * 32 + (lane >> 4) * 8;
    size_t o = (size_t)idx * 8;
    for (int j = 0; j < 8; ++j) {
        float v = A[(size_t)(kbase + j) * H + n];
        if (Bp) v += Bp[(size_t)(kbase + j) * H + n];
        short h = f2bf(v);
        whi[o + j] = h;
        wlo[o + j] = f2bf(v - bf2f(h));
    }
}

// ---------------- segment mean (gather over CSR), 8-way edge unroll ----------------

__global__ __launch_bounds__(256) void agg_mean_kernel(const float* __restrict__ x,
                                                       const int* __restrict__ rowptr,
                                                       const int* __restrict__ col,
                                                       float* __restrict__ out, int n_dst) {
    int w = (blockIdx.x << 2) + (threadIdx.x >> 6);
    int lane = threadIdx.x & 63;
    if (w >= n_dst) return;
    int beg = rowptr[w], end = rowptr[w + 1];
    int off = lane * 2;
    float ax[8], ay[8];
#pragma unroll
    for (int i = 0; i < 8; ++i) { ax[i] = 0.f; ay[i] = 0.f; }
    int e = beg;
    for (; e + 7 < end; e += 8) {
        int s[8];
#pragma unroll
        for (int i = 0; i < 8; ++i) s[i] = col[e + i];
#pragma unroll
        for (int i = 0; i < 8; ++i) {
            float2 v = *(const float2*)&x[(size_t)s[i] * H + off];
            ax[i] += v.x; ay[i] += v.y;
        }
    }
    for (; e < end; ++e) {
        int s = col[e];
        float2 v = *(const float2*)&x[(size_t)s * H + off];
        ax[0] += v.x; ay[0] += v.y;
    }
    float sx = ((ax[0] + ax[1]) + (ax[2] + ax[3])) + ((ax[4] + ax[5]) + (ax[6] + ax[7]));
    float sy = ((ay[0] + ay[1]) + (ay[2] + ay[3])) + ((ay[4] + ay[5]) + (ay[6] + ay[7]));
    int c = end - beg; if (c < 1) c = 1;
    float inv = 1.0f / (float)c;
    float2 r; r.x = sx * inv; r.y = sy * inv;
    *(float2*)&out[(size_t)w * H + off] = r;
}

// ---------------- split-bf16 MFMA GEMM, double-buffered B prefetch ----------------
// out[r,:] = sum_m A_m[r,:] @ W_m + b0 (+ b1), optional leaky relu.
// fp32 emulated as 3 bf16 MFMAs: ah*wh + al*wh + ah*wl (err ~2^-16 rel; R4-verified 0.0039).
// Block: 64 rows x 128 cols, 4 waves. Wave = ALL 64 rows x 2 col-tiles (ct0=2*wave, +1):
// B-frags per kc = 4 loads/wave (own columns only, no cross-wave redundancy), batched and
// double-buffered across kc; next matrix's kc0 prefetched before the staging barrier.
// In-place safe when out == A_m: block stages (reads) only its own 64 rows, writes at end.

template <int NIN>
__global__ __launch_bounds__(256, 3) void gemm_mfma(
    const float* __restrict__ A0, const float* __restrict__ A1, const float* __restrict__ A2,
    const short* __restrict__ whi, const short* __restrict__ wlo,
    int mat0, int mat1, int mat2,
    const float* __restrict__ b0, const float* __restrict__ b1,
    float* __restrict__ out, int n_rows, int relu) {
    __shared__ short Ahi[64 * RS];
    __shared__ short Alo[64 * RS];
    const int tid = threadIdx.x;
    const int lane = tid & 63;
    const int wave = tid >> 6;
    const int r0 = blockIdx.x * 64;
    const int ct0 = wave * 2;             // this wave's first col-tile
    const int m16 = lane & 15;            // row within m-tile
    const int acol = (lane >> 4) * 8;     // k offset within kc chunk

    f32x4 acc[4][2];
#pragma unroll
    for (int mt = 0; mt < 4; ++mt)
#pragma unroll
        for (int c = 0; c < 2; ++c) acc[mt][c] = (f32x4){0.f, 0.f, 0.f, 0.f};

    const float* Aarr[3] = {A0, A1, A2};
    const int marr[3] = {mat0, mat1, mat2};

    short8 bh[2][2], bl[2][2];
    // prefetch m=0, kc=0 (no LDS dependency -> overlaps first barrier + staging)
    {
        const short* wh = whi + (size_t)marr[0] * (H * H);
        const short* wl = wlo + (size_t)marr[0] * (H * H);
        size_t f0 = ((size_t)ct0 * 64 + lane) * 8;
        bh[0][0] = *(const short8*)&wh[f0];
        bh[0][1] = *(const short8*)&wh[f0 + 512];
        bl[0][0] = *(const short8*)&wl[f0];
        bl[0][1] = *(const short8*)&wl[f0 + 512];
    }

#pragma unroll
    for (int m = 0; m < NIN; ++m) {
        const float* __restrict__ A = Aarr[m];
        const short* __restrict__ wh = whi + (size_t)marr[m] * (H * H);
        const short* __restrict__ wl = wlo + (size_t)marr[m] * (H * H);
        __syncthreads();   // previous m's LDS readers done
#pragma unroll
        for (int i = 0; i < 8; ++i) {
            int f = tid + i * 256;        // float4 unit 0..2047
            int row = f >> 5;             // 32 float4 per row
            int c4 = (f & 31) * 4;
            int gr = r0 + row;
            if (gr >= n_rows) gr = n_rows - 1;
            float4 v = *(const float4*)&A[(size_t)gr * H + c4];
            short h0 = f2bf(v.x), h1 = f2bf(v.y), h2 = f2bf(v.z), h3 = f2bf(v.w);
            *(short4v*)&Ahi[row * RS + c4] = (short4v){h0, h1, h2, h3};
            *(short4v*)&Alo[row * RS + c4] =
                (short4v){f2bf(v.x - bf2f(h0)), f2bf(v.y - bf2f(h1)),
                          f2bf(v.z - bf2f(h2)), f2bf(v.w - bf2f(h3))};
        }
        __syncthreads();
#pragma unroll
        for (int kc = 0; kc < 4; ++kc) {
            if (kc < 3) {           // prefetch next kc into alternate bank
                int nb = (kc + 1) & 1;
                size_t f = ((size_t)((kc + 1) * 8 + ct0) * 64 + lane) * 8;
                bh[nb][0] = *(const short8*)&wh[f];
                bh[nb][1] = *(const short8*)&wh[f + 512];
                bl[nb][0] = *(const short8*)&wl[f];
                bl[nb][1] = *(const short8*)&wl[f + 512];
            } else if (m + 1 < NIN) {  // prefetch next matrix's kc0 into bank 0
                const short* wh2 = whi + (size_t)marr[m + 1] * (H * H);
                const short* wl2 = wlo + (size_t)marr[m + 1] * (H * H);
                size_t f = ((size_t)ct0 * 64 + lane) * 8;
                bh[0][0] = *(const short8*)&wh2[f];
                bh[0][1] = *(const short8*)&wh2[f + 512];
                bl[0][0] = *(const short8*)&wl2[f];
                bl[0][1] = *(const short8*)&wl2[f + 512];
            }
            int cb = kc & 1;
#pragma unroll
            for (int mt = 0; mt < 4; ++mt) {
                short8 ah = *(const short8*)&Ahi[(mt * 16 + m16) * RS + kc * 32 + acol];
                short8 al = *(const short8*)&Alo[(mt * 16 + m16) * RS + kc * 32 + acol];
#pragma unroll
                for (int c = 0; c < 2; ++c) {
                    acc[mt][c] = __builtin_amdgcn_mfma_f32_16x16x32_bf16(ah, bh[cb][c], acc[mt][c], 0, 0, 0);
                    acc[mt][c] = __builtin_amdgcn_mfma_f32_16x16x32_bf16(al, bh[cb][c], acc[mt][c], 0, 0, 0);
                    acc[mt][c] = __builtin_amdgcn_mfma_f32_16x16x32_bf16(ah, bl[cb][c], acc[mt][c], 0, 0, 0);
                }
            }
        }
    }

    // epilogue: C/D layout col = lane&15, row = (lane>>4)*4 + reg
    const int rquad = (lane >> 4) * 4;
    const int ncol = lane & 15;
#pragma unroll
    for (int c = 0; c < 2; ++c) {
        int n = (ct0 + c) * 16 + ncol;
        float bs = b0[n];
        if (b1) bs += b1[n];
#pragma unroll
        for (int mt = 0; mt < 4; ++mt) {
#pragma unroll
            for (int reg = 0; reg < 4; ++reg) {
                int gr = r0 + mt * 16 + rquad + reg;
                if (gr < n_rows) {
                    float v = acc[mt][c][reg] + bs;
                    if (relu) v = v > 0.f ? v : 0.01f * v;
                    out[(size_t)gr * H + n] = v;
                }
            }
        }
    }
}

// ---------------- edge decoder: sigmoid(dot(xp[i], xg[j])) ----------------

__global__ __launch_bounds__(256) void scores_kernel(const float* __restrict__ xp,
                                                     const float* __restrict__ xg,
                                                     const int* __restrict__ eli, int E,
                                                     float* __restrict__ out) {
    int lane16 = threadIdx.x & 15;
    int sub = threadIdx.x >> 4;     // 16 edges per block
    int e = blockIdx.x * 16 + sub;
    if (e >= E) return;
    int ip = eli[e];
    int ig = eli[E + e];
    const float4* p = (const float4*)&xp[(size_t)ip * H];
    const float4* g = (const float4*)&xg[(size_t)ig * H];
    float4 a0 = p[lane16], a1 = p[lane16 + 16];
    float4 b0 = g[lane16], b1 = g[lane16 + 16];
    float s = a0.x * b0.x + a0.y * b0.y + a0.z * b0.z + a0.w * b0.w
            + a1.x * b1.x + a1.y * b1.y + a1.z * b1.z + a1.w * b1.w;
#pragma unroll
    for (int off = 8; off; off >>= 1) s += __shfl_xor(s, off, 16);
    if (lane16 == 0) out[e] = 1.0f / (1.0f + expf(-s));
}

// ---------------- host ----------------

extern "C" void kernel_launch(void* const* d_in, const int* in_sizes, int n_in,
                              void* d_out, int out_size, void* d_ws, size_t ws_size,
                              hipStream_t stream) {
    const float* x_pheno = (const float*)d_in[0];
    const float* x_gene  = (const float*)d_in[1];
    const float* Wl_isa  = (const float*)d_in[2];
    const float* bl_isa  = (const float*)d_in[3];
    const float* Wr_isa  = (const float*)d_in[4];
    const float* Wl_rel  = (const float*)d_in[5];
    const float* bl_rel  = (const float*)d_in[6];
    const float* Wr_rel  = (const float*)d_in[7];
    const float* Wl_rev  = (const float*)d_in[8];
    const float* bl_rev  = (const float*)d_in[9];
    const float* Wr_rev  = (const float*)d_in[10];
    const int* e_isa = (const int*)d_in[11];
    const int* e_rel = (const int*)d_in[12];
    const int* e_rev = (const int*)d_in[13];
    const int* e_lbl = (const int*)d_in[14];
    const int E_isa = in_sizes[11] / 2;
    const int E_rel = in_sizes[12] / 2;
    const int E_rev = in_sizes[13] / 2;
    const int E_lbl = in_sizes[14] / 2;
    const int NP = in_sizes[0] / H;
    const int NG = in_sizes[1] / H;
    const int NMAX = NP > NG ? NP : NG;
    const int n_tot = NP + NG + NP;
    const int E_tot = E_isa + E_rel + E_rev;
    const int nb = (n_tot + 1023) / 1024;

    char* ws = (char*)d_ws;
    auto alloc = [&](size_t bytes) -> char* {
        char* p = ws;
        ws += (bytes + 255) & ~(size_t)255;
        return p;
    };
    float* B[5];
    for (int i = 0; i < 5; ++i) B[i] = (float*)alloc((size_t)NMAX * H * sizeof(float));
    int* cnt    = (int*)alloc((size_t)n_tot * 4);
    int* rowptr = (int*)alloc((size_t)(n_tot + 1) * 4);
    int* cursor = (int*)alloc((size_t)n_tot * 4);
    int* col    = (int*)alloc((size_t)E_tot * 4);
    int* partial = (int*)alloc((size_t)1024 * 4);
    short* whi = (short*)alloc((size_t)15 * H * H * sizeof(short));  // packed bf16-hi W frags
    short* wlo = (short*)alloc((size_t)15 * H * H * sizeof(short));  // packed bf16-lo W frags

    int* cnt_isa = cnt;             // dst in [0,NP)
    int* cnt_rel = cnt + NP;        // dst in [0,NG)
    int* cnt_rev = cnt + NP + NG;   // dst in [0,NP)
    const int* rp_isa = rowptr;
    const int* rp_rel = rowptr + NP;
    const int* rp_rev = rowptr + NP + NG;

    // ---- CSR build (every call; ws is re-poisoned by the harness) ----
    hipMemsetAsync(cnt, 0, (size_t)n_tot * 4, stream);
    count_kernel<<<(E_isa + 255) / 256, 256, 0, stream>>>(e_isa, E_isa, cnt_isa);
    count_kernel<<<(E_rel + 255) / 256, 256, 0, stream>>>(e_rel, E_rel, cnt_rel);
    count_kernel<<<(E_rev + 255) / 256, 256, 0, stream>>>(e_rev, E_rev, cnt_rev);
    scan_pass1<<<nb, 256, 0, stream>>>(cnt, n_tot, partial);
    scan_pass2<<<1, 1024, 0, stream>>>(partial, nb, &rowptr[n_tot]);
    scan_pass3<<<nb, 256, 0, stream>>>(cnt, n_tot, partial, rowptr, cursor);
    fill_kernel<<<(E_isa + 255) / 256, 256, 0, stream>>>(e_isa, E_isa, cursor, col);
    fill_kernel<<<(E_rel + 255) / 256, 256, 0, stream>>>(e_rel, E_rel, cursor + NP, col);
    fill_kernel<<<(E_rev + 255) / 256, 256, 0, stream>>>(e_rev, E_rev, cursor + NP + NG, col);

    // ---- W pack: per layer slots {Wl_isa, Wl_rev, Wsum=Wr_isa+Wr_rev, Wl_rel, Wr_rel} ----
    WSrc src;
    for (int l = 0; l < 3; ++l) {
        src.a[l * 5 + 0] = Wl_isa + (size_t)l * H * H;  src.b[l * 5 + 0] = nullptr;
        src.a[l * 5 + 1] = Wl_rev + (size_t)l * H * H;  src.b[l * 5 + 1] = nullptr;
        src.a[l * 5 + 2] = Wr_isa + (size_t)l * H * H;  src.b[l * 5 + 2] = Wr_rev + (size_t)l * H * H;
        src.a[l * 5 + 3] = Wl_rel + (size_t)l * H * H;  src.b[l * 5 + 3] = nullptr;
        src.a[l * 5 + 4] = Wr_rel + (size_t)l * H * H;  src.b[l * 5 + 4] = nullptr;
    }
    pack_w_kernel<<<(15 * 4 * 8 * 64 + 255) / 256, 256, 0, stream>>>(src, whi, wlo);

    // ---- 3 layers ----
    // buffers: layer0 M1=B0 M2=B1 M3=B2; layer1 M1=B3 M2=B1 M3=B4; layer2 M1=B0 M2=B1 M3=B2
    int mi[3] = {0, 3, 0}, mv[3] = {1, 1, 1}, mr[3] = {2, 4, 2};
    const float* xp = x_pheno;
    const float* xg = x_gene;
    for (int l = 0; l < 3; ++l) {
        float* M1 = B[mi[l]];
        float* M2 = B[mv[l]];
        float* M3 = B[mr[l]];
        agg_mean_kernel<<<(NP + 3) / 4, 256, 0, stream>>>(xp, rp_isa, col, M1, NP);
        agg_mean_kernel<<<(NP + 3) / 4, 256, 0, stream>>>(xg, rp_rev, col, M2, NP);
        agg_mean_kernel<<<(NG + 3) / 4, 256, 0, stream>>>(xp, rp_rel, col, M3, NG);
        int relu = (l < 2) ? 1 : 0;
        const float* bli = bl_isa + (size_t)l * H;
        const float* blv = bl_rev + (size_t)l * H;
        const float* blr = bl_rel + (size_t)l * H;
        // new_p = M1@Wl_isa + M2@Wl_rev + xp@(Wr_isa+Wr_rev) + bl_isa + bl_rev -> M1 (in-place)
        gemm_mfma<3><<<(NP + 63) / 64, 256, 0, stream>>>(
            M1, M2, xp, whi, wlo, l * 5 + 0, l * 5 + 1, l * 5 + 2, bli, blv, M1, NP, relu);
        // new_g = M3@Wl_rel + xg@Wr_rel + bl_rel -> M3 (in-place)
        gemm_mfma<2><<<(NG + 63) / 64, 256, 0, stream>>>(
            M3, xg, nullptr, whi, wlo, l * 5 + 3, l * 5 + 4, 0, blr, nullptr, M3, NG, relu);
        xp = M1;
        xg = M3;
    }

    // ---- decoder ----
    scores_kernel<<<(E_lbl + 15) / 16, 256, 0, stream>>>(xp, xg, e_lbl, E_lbl, (float*)d_out);
}

// Round 7
// 1116.357 us; speedup vs baseline: 1.8345x; 1.0227x over previous
//
#include <hip/hip_runtime.h>
#include <hip/hip_bf16.h>
#include <math.h>

#define H 128
#define RS 136  // LDS row stride in shorts (128 + 8 pad; keeps ds_read_b128 16B-aligned)

typedef __attribute__((ext_vector_type(8))) short short8;
typedef __attribute__((ext_vector_type(4))) short short4v;
typedef __attribute__((ext_vector_type(4))) float f32x4;

// fp32 -> bf16 (RNE); values here are finite (no NaN handling needed)
__device__ __forceinline__ short f2bf(float f) {
    unsigned u = __float_as_uint(f);
    u += 0x7fff + ((u >> 16) & 1);
    return (short)(u >> 16);
}
__device__ __forceinline__ float bf2f(short h) {
    return __uint_as_float(((unsigned)(unsigned short)h) << 16);
}

// ---------------- CSR build ----------------
// Counts/offsets for all 3 edge types in ONE concatenated space [NP(isa) | NG(rel) | NP(rev)].
// One merged count kernel + one merged fill kernel (fewer BW-bound dispatch tails).

__global__ __launch_bounds__(256) void count_all_kernel(
    const int* __restrict__ e0, int E0, const int* __restrict__ e1, int E1,
    const int* __restrict__ e2, int E2, int* __restrict__ cnt, int NPn, int NGn) {
    int g = blockIdx.x * 256 + threadIdx.x;
    const int* ed; int E, lo, base;
    if (g < E0) { ed = e0; E = E0; lo = g; base = 0; }
    else if (g < E0 + E1) { ed = e1; E = E1; lo = g - E0; base = NPn; }
    else if (g < E0 + E1 + E2) { ed = e2; E = E2; lo = g - E0 - E1; base = NPn + NGn; }
    else return;
    atomicAdd(&cnt[base + ed[E + lo]], 1);
}

__global__ __launch_bounds__(256) void fill_all_kernel(
    const int* __restrict__ e0, int E0, const int* __restrict__ e1, int E1,
    const int* __restrict__ e2, int E2, int* __restrict__ cursor,
    int* __restrict__ col, int NPn, int NGn) {
    int g = blockIdx.x * 256 + threadIdx.x;
    const int* ed; int E, lo, base;
    if (g < E0) { ed = e0; E = E0; lo = g; base = 0; }
    else if (g < E0 + E1) { ed = e1; E = E1; lo = g - E0; base = NPn; }
    else if (g < E0 + E1 + E2) { ed = e2; E = E2; lo = g - E0 - E1; base = NPn + NGn; }
    else return;
    int src = ed[lo];
    int dst = ed[E + lo];
    col[atomicAdd(&cursor[base + dst], 1)] = src;
}

__global__ __launch_bounds__(256) void scan_pass1(const int* __restrict__ cnt, int n,
                                                  int* __restrict__ partial) {
    int base = blockIdx.x * 1024 + threadIdx.x * 4;
    int s = 0;
    if (base + 3 < n) {
        int4 v = *(const int4*)&cnt[base];
        s = v.x + v.y + v.z + v.w;
    } else {
        for (int i = 0; i < 4; ++i) if (base + i < n) s += cnt[base + i];
    }
    __shared__ int red[256];
    red[threadIdx.x] = s;
    __syncthreads();
    for (int off = 128; off; off >>= 1) {
        if (threadIdx.x < off) red[threadIdx.x] += red[threadIdx.x + off];
        __syncthreads();
    }
    if (threadIdx.x == 0) partial[blockIdx.x] = red[0];
}

__global__ __launch_bounds__(1024) void scan_pass2(int* __restrict__ partial, int nb,
                                                   int* __restrict__ total_out) {
    __shared__ int sh[1024];
    int t = threadIdx.x;
    int v = (t < nb) ? partial[t] : 0;
    sh[t] = v;
    __syncthreads();
    for (int off = 1; off < 1024; off <<= 1) {
        int u = (t >= off) ? sh[t - off] : 0;
        __syncthreads();
        sh[t] += u;
        __syncthreads();
    }
    if (t < nb) partial[t] = sh[t] - v;   // exclusive
    if (t == 1023) *total_out = sh[1023];
}

__global__ __launch_bounds__(256) void scan_pass3(const int* __restrict__ cnt, int n,
                                                  const int* __restrict__ partial,
                                                  int* __restrict__ rowptr,
                                                  int* __restrict__ cursor) {
    int t = threadIdx.x;
    int base = blockIdx.x * 1024 + t * 4;
    int v[4];
    int s = 0;
    for (int i = 0; i < 4; ++i) {
        v[i] = (base + i < n) ? cnt[base + i] : 0;
        s += v[i];
    }
    __shared__ int sh[256];
    sh[t] = s;
    __syncthreads();
    for (int off = 1; off < 256; off <<= 1) {
        int u = (t >= off) ? sh[t - off] : 0;
        __syncthreads();
        sh[t] += u;
        __syncthreads();
    }
    int run = partial[blockIdx.x] + sh[t] - s;
    for (int i = 0; i < 4; ++i) {
        int idx = base + i;
        if (idx < n) {
            rowptr[idx] = run;
            cursor[idx] = run;
            run += v[i];
        }
    }
}

// ---------------- W pack: fp32 [k][n] -> MFMA B-fragment order, split bf16 hi/lo ----------------
// 15 matrices (5 per layer: Wl_isa, Wl_rev, Wsum=Wr_isa+Wr_rev, Wl_rel, Wr_rel).
// Fragment order: [mat][kc][ct][lane][j] (j=0..7): a wave's (kc,ct) frag = 16B/lane coalesced.
// B-operand layout: n = ct*16 + (lane&15), k = kc*32 + (lane>>4)*8 + j.

struct WSrc { const float* a[15]; const float* b[15]; };

__global__ __launch_bounds__(256) void pack_w_kernel(WSrc src, short* __restrict__ whi,
                                                     short* __restrict__ wlo) {
    int idx = blockIdx.x * 256 + threadIdx.x;   // (mat, kc, ct, lane)
    if (idx >= 15 * 4 * 8 * 64) return;
    int lane = idx & 63;
    int ct = (idx >> 6) & 7;
    int kc = (idx >> 9) & 3;
    int mat = idx >> 11;
    const float* A = src.a[mat];
    const float* Bp = src.b[mat];
    int n = ct * 16 + (lane & 15);
    int kbase = kc * 32 + (lane >> 4) * 8;
    size_t o = (size_t)idx * 8;
    for (int j = 0; j < 8; ++j) {
        float v = A[(size_t)(kbase + j) * H + n];
        if (Bp) v += Bp[(size_t)(kbase + j) * H + n];
        short h = f2bf(v);
        whi[o + j] = h;
        wlo[o + j] = f2bf(v - bf2f(h));
    }
}

// ---------------- merged per-layer segment mean ----------------
// One dispatch per layer. Wave w < NP: isa-mean(xp)->M1[w] AND rev-mean(xg)->M2[w].
// Wave w in [NP, NP+NG): rel-mean(xp)->M3[w-NP]. 8-way edge unroll per loop.

__device__ __forceinline__ float2 seg_mean(const float* __restrict__ x,
                                           const int* __restrict__ col,
                                           int beg, int end, int off) {
    float ax[8], ay[8];
#pragma unroll
    for (int i = 0; i < 8; ++i) { ax[i] = 0.f; ay[i] = 0.f; }
    int e = beg;
    for (; e + 7 < end; e += 8) {
        int s[8];
#pragma unroll
        for (int i = 0; i < 8; ++i) s[i] = col[e + i];
#pragma unroll
        for (int i = 0; i < 8; ++i) {
            float2 v = *(const float2*)&x[(size_t)s[i] * H + off];
            ax[i] += v.x; ay[i] += v.y;
        }
    }
    for (; e < end; ++e) {
        float2 v = *(const float2*)&x[(size_t)col[e] * H + off];
        ax[0] += v.x; ay[0] += v.y;
    }
    float sx = ((ax[0] + ax[1]) + (ax[2] + ax[3])) + ((ax[4] + ax[5]) + (ax[6] + ax[7]));
    float sy = ((ay[0] + ay[1]) + (ay[2] + ay[3])) + ((ay[4] + ay[5]) + (ay[6] + ay[7]));
    int c = end - beg; if (c < 1) c = 1;
    float inv = 1.0f / (float)c;
    return (float2){sx * inv, sy * inv};
}

__global__ __launch_bounds__(256) void agg_all_kernel(
    const float* __restrict__ xp, const float* __restrict__ xg,
    const int* __restrict__ rowptr, const int* __restrict__ col,
    float* __restrict__ M1, float* __restrict__ M2, float* __restrict__ M3,
    int NPn, int NGn) {
    int w = (blockIdx.x << 2) + (threadIdx.x >> 6);
    int lane = threadIdx.x & 63;
    int off = lane * 2;
    if (w < NPn) {
        float2 r1 = seg_mean(xp, col, rowptr[w], rowptr[w + 1], off);
        *(float2*)&M1[(size_t)w * H + off] = r1;
        int b = NPn + NGn + w;
        float2 r2 = seg_mean(xg, col, rowptr[b], rowptr[b + 1], off);
        *(float2*)&M2[(size_t)w * H + off] = r2;
    } else if (w < NPn + NGn) {
        float2 r3 = seg_mean(xp, col, rowptr[w], rowptr[w + 1], off);
        *(float2*)&M3[(size_t)(w - NPn) * H + off] = r3;
    }
}

// ---------------- split-bf16 MFMA GEMM, double-buffered B prefetch (R6, proven) ----------------
// out[r,:] = sum_m A_m[r,:] @ W_m + b0 (+ b1), optional leaky relu.
// fp32 emulated as 3 bf16 MFMAs: ah*wh + al*wh + ah*wl (err ~2^-16 rel).
// Block: 64 rows x 128 cols, 4 waves; wave = all 64 rows x 2 col-tiles (no B redundancy).
// In-place safe when out == A_m: block stages (reads) only its own 64 rows, writes at end.

template <int NIN>
__global__ __launch_bounds__(256, 3) void gemm_mfma(
    const float* __restrict__ A0, const float* __restrict__ A1, const float* __restrict__ A2,
    const short* __restrict__ whi, const short* __restrict__ wlo,
    int mat0, int mat1, int mat2,
    const float* __restrict__ b0, const float* __restrict__ b1,
    float* __restrict__ out, int n_rows, int relu) {
    __shared__ short Ahi[64 * RS];
    __shared__ short Alo[64 * RS];
    const int tid = threadIdx.x;
    const int lane = tid & 63;
    const int wave = tid >> 6;
    const int r0 = blockIdx.x * 64;
    const int ct0 = wave * 2;
    const int m16 = lane & 15;
    const int acol = (lane >> 4) * 8;

    f32x4 acc[4][2];
#pragma unroll
    for (int mt = 0; mt < 4; ++mt)
#pragma unroll
        for (int c = 0; c < 2; ++c) acc[mt][c] = (f32x4){0.f, 0.f, 0.f, 0.f};

    const float* Aarr[3] = {A0, A1, A2};
    const int marr[3] = {mat0, mat1, mat2};

    short8 bh[2][2], bl[2][2];
    {
        const short* wh = whi + (size_t)marr[0] * (H * H);
        const short* wl = wlo + (size_t)marr[0] * (H * H);
        size_t f0 = ((size_t)ct0 * 64 + lane) * 8;
        bh[0][0] = *(const short8*)&wh[f0];
        bh[0][1] = *(const short8*)&wh[f0 + 512];
        bl[0][0] = *(const short8*)&wl[f0];
        bl[0][1] = *(const short8*)&wl[f0 + 512];
    }

#pragma unroll
    for (int m = 0; m < NIN; ++m) {
        const float* __restrict__ A = Aarr[m];
        const short* __restrict__ wh = whi + (size_t)marr[m] * (H * H);
        const short* __restrict__ wl = wlo + (size_t)marr[m] * (H * H);
        __syncthreads();
#pragma unroll
        for (int i = 0; i < 8; ++i) {
            int f = tid + i * 256;
            int row = f >> 5;
            int c4 = (f & 31) * 4;
            int gr = r0 + row;
            if (gr >= n_rows) gr = n_rows - 1;
            float4 v = *(const float4*)&A[(size_t)gr * H + c4];
            short h0 = f2bf(v.x), h1 = f2bf(v.y), h2 = f2bf(v.z), h3 = f2bf(v.w);
            *(short4v*)&Ahi[row * RS + c4] = (short4v){h0, h1, h2, h3};
            *(short4v*)&Alo[row * RS + c4] =
                (short4v){f2bf(v.x - bf2f(h0)), f2bf(v.y - bf2f(h1)),
                          f2bf(v.z - bf2f(h2)), f2bf(v.w - bf2f(h3))};
        }
        __syncthreads();
#pragma unroll
        for (int kc = 0; kc < 4; ++kc) {
            if (kc < 3) {
                int nb = (kc + 1) & 1;
                size_t f = ((size_t)((kc + 1) * 8 + ct0) * 64 + lane) * 8;
                bh[nb][0] = *(const short8*)&wh[f];
                bh[nb][1] = *(const short8*)&wh[f + 512];
                bl[nb][0] = *(const short8*)&wl[f];
                bl[nb][1] = *(const short8*)&wl[f + 512];
            } else if (m + 1 < NIN) {
                const short* wh2 = whi + (size_t)marr[m + 1] * (H * H);
                const short* wl2 = wlo + (size_t)marr[m + 1] * (H * H);
                size_t f = ((size_t)ct0 * 64 + lane) * 8;
                bh[0][0] = *(const short8*)&wh2[f];
                bh[0][1] = *(const short8*)&wh2[f + 512];
                bl[0][0] = *(const short8*)&wl2[f];
                bl[0][1] = *(const short8*)&wl2[f + 512];
            }
            int cb = kc & 1;
#pragma unroll
            for (int mt = 0; mt < 4; ++mt) {
                short8 ah = *(const short8*)&Ahi[(mt * 16 + m16) * RS + kc * 32 + acol];
                short8 al = *(const short8*)&Alo[(mt * 16 + m16) * RS + kc * 32 + acol];
#pragma unroll
                for (int c = 0; c < 2; ++c) {
                    acc[mt][c] = __builtin_amdgcn_mfma_f32_16x16x32_bf16(ah, bh[cb][c], acc[mt][c], 0, 0, 0);
                    acc[mt][c] = __builtin_amdgcn_mfma_f32_16x16x32_bf16(al, bh[cb][c], acc[mt][c], 0, 0, 0);
                    acc[mt][c] = __builtin_amdgcn_mfma_f32_16x16x32_bf16(ah, bl[cb][c], acc[mt][c], 0, 0, 0);
                }
            }
        }
    }

    const int rquad = (lane >> 4) * 4;
    const int ncol = lane & 15;
#pragma unroll
    for (int c = 0; c < 2; ++c) {
        int n = (ct0 + c) * 16 + ncol;
        float bs = b0[n];
        if (b1) bs += b1[n];
#pragma unroll
        for (int mt = 0; mt < 4; ++mt) {
#pragma unroll
            for (int reg = 0; reg < 4; ++reg) {
                int gr = r0 + mt * 16 + rquad + reg;
                if (gr < n_rows) {
                    float v = acc[mt][c][reg] + bs;
                    if (relu) v = v > 0.f ? v : 0.01f * v;
                    out[(size_t)gr * H + n] = v;
                }
            }
        }
    }
}

// ---------------- edge decoder: sigmoid(dot(xp[i], xg[j])) ----------------

__global__ __launch_bounds__(256) void scores_kernel(const float* __restrict__ xp,
                                                     const float* __restrict__ xg,
                                                     const int* __restrict__ eli, int E,
                                                     float* __restrict__ out) {
    int lane16 = threadIdx.x & 15;
    int sub = threadIdx.x >> 4;     // 16 edges per block
    int e = blockIdx.x * 16 + sub;
    if (e >= E) return;
    int ip = eli[e];
    int ig = eli[E + e];
    const float4* p = (const float4*)&xp[(size_t)ip * H];
    const float4* g = (const float4*)&xg[(size_t)ig * H];
    float4 a0 = p[lane16], a1 = p[lane16 + 16];
    float4 b0 = g[lane16], b1 = g[lane16 + 16];
    float s = a0.x * b0.x + a0.y * b0.y + a0.z * b0.z + a0.w * b0.w
            + a1.x * b1.x + a1.y * b1.y + a1.z * b1.z + a1.w * b1.w;
#pragma unroll
    for (int off = 8; off; off >>= 1) s += __shfl_xor(s, off, 16);
    if (lane16 == 0) out[e] = 1.0f / (1.0f + expf(-s));
}

// ---------------- host ----------------

extern "C" void kernel_launch(void* const* d_in, const int* in_sizes, int n_in,
                              void* d_out, int out_size, void* d_ws, size_t ws_size,
                              hipStream_t stream) {
    const float* x_pheno = (const float*)d_in[0];
    const float* x_gene  = (const float*)d_in[1];
    const float* Wl_isa  = (const float*)d_in[2];
    const float* bl_isa  = (const float*)d_in[3];
    const float* Wr_isa  = (const float*)d_in[4];
    const float* Wl_rel  = (const float*)d_in[5];
    const float* bl_rel  = (const float*)d_in[6];
    const float* Wr_rel  = (const float*)d_in[7];
    const float* Wl_rev  = (const float*)d_in[8];
    const float* bl_rev  = (const float*)d_in[9];
    const float* Wr_rev  = (const float*)d_in[10];
    const int* e_isa = (const int*)d_in[11];
    const int* e_rel = (const int*)d_in[12];
    const int* e_rev = (const int*)d_in[13];
    const int* e_lbl = (const int*)d_in[14];
    const int E_isa = in_sizes[11] / 2;
    const int E_rel = in_sizes[12] / 2;
    const int E_rev = in_sizes[13] / 2;
    const int E_lbl = in_sizes[14] / 2;
    const int NP = in_sizes[0] / H;
    const int NG = in_sizes[1] / H;
    const int NMAX = NP > NG ? NP : NG;
    const int n_tot = NP + NG + NP;
    const int E_tot = E_isa + E_rel + E_rev;
    const int nb = (n_tot + 1023) / 1024;

    char* ws = (char*)d_ws;
    auto alloc = [&](size_t bytes) -> char* {
        char* p = ws;
        ws += (bytes + 255) & ~(size_t)255;
        return p;
    };
    float* B[5];
    for (int i = 0; i < 5; ++i) B[i] = (float*)alloc((size_t)NMAX * H * sizeof(float));
    int* cnt    = (int*)alloc((size_t)n_tot * 4);
    int* rowptr = (int*)alloc((size_t)(n_tot + 1) * 4);
    int* cursor = (int*)alloc((size_t)n_tot * 4);
    int* col    = (int*)alloc((size_t)E_tot * 4);
    int* partial = (int*)alloc((size_t)1024 * 4);
    short* whi = (short*)alloc((size_t)15 * H * H * sizeof(short));  // packed bf16-hi W frags
    short* wlo = (short*)alloc((size_t)15 * H * H * sizeof(short));  // packed bf16-lo W frags

    // ---- CSR build (every call; ws is re-poisoned by the harness) ----
    hipMemsetAsync(cnt, 0, (size_t)n_tot * 4, stream);
    count_all_kernel<<<(E_tot + 255) / 256, 256, 0, stream>>>(
        e_isa, E_isa, e_rel, E_rel, e_rev, E_rev, cnt, NP, NG);
    scan_pass1<<<nb, 256, 0, stream>>>(cnt, n_tot, partial);
    scan_pass2<<<1, 1024, 0, stream>>>(partial, nb, &rowptr[n_tot]);
    scan_pass3<<<nb, 256, 0, stream>>>(cnt, n_tot, partial, rowptr, cursor);
    fill_all_kernel<<<(E_tot + 255) / 256, 256, 0, stream>>>(
        e_isa, E_isa, e_rel, E_rel, e_rev, E_rev, cursor, col, NP, NG);

    // ---- W pack: per layer slots {Wl_isa, Wl_rev, Wsum=Wr_isa+Wr_rev, Wl_rel, Wr_rel} ----
    WSrc src;
    for (int l = 0; l < 3; ++l) {
        src.a[l * 5 + 0] = Wl_isa + (size_t)l * H * H;  src.b[l * 5 + 0] = nullptr;
        src.a[l * 5 + 1] = Wl_rev + (size_t)l * H * H;  src.b[l * 5 + 1] = nullptr;
        src.a[l * 5 + 2] = Wr_isa + (size_t)l * H * H;  src.b[l * 5 + 2] = Wr_rev + (size_t)l * H * H;
        src.a[l * 5 + 3] = Wl_rel + (size_t)l * H * H;  src.b[l * 5 + 3] = nullptr;
        src.a[l * 5 + 4] = Wr_rel + (size_t)l * H * H;  src.b[l * 5 + 4] = nullptr;
    }
    pack_w_kernel<<<(15 * 4 * 8 * 64 + 255) / 256, 256, 0, stream>>>(src, whi, wlo);

    // ---- 3 layers ----
    // buffers: layer0 M1=B0 M2=B1 M3=B2; layer1 M1=B3 M2=B1 M3=B4; layer2 M1=B0 M2=B1 M3=B2
    int mi[3] = {0, 3, 0}, mv[3] = {1, 1, 1}, mr[3] = {2, 4, 2};
    const float* xp = x_pheno;
    const float* xg = x_gene;
    for (int l = 0; l < 3; ++l) {
        float* M1 = B[mi[l]];
        float* M2 = B[mv[l]];
        float* M3 = B[mr[l]];
        agg_all_kernel<<<(NP + NG + 3) / 4, 256, 0, stream>>>(
            xp, xg, rowptr, col, M1, M2, M3, NP, NG);
        int relu = (l < 2) ? 1 : 0;
        const float* bli = bl_isa + (size_t)l * H;
        const float* blv = bl_rev + (size_t)l * H;
        const float* blr = bl_rel + (size_t)l * H;
        // new_p = M1@Wl_isa + M2@Wl_rev + xp@(Wr_isa+Wr_rev) + bl_isa + bl_rev -> M1 (in-place)
        gemm_mfma<3><<<(NP + 63) / 64, 256, 0, stream>>>(
            M1, M2, xp, whi, wlo, l * 5 + 0, l * 5 + 1, l * 5 + 2, bli, blv, M1, NP, relu);
        // new_g = M3@Wl_rel + xg@Wr_rel + bl_rel -> M3 (in-place)
        gemm_mfma<2><<<(NG + 63) / 64, 256, 0, stream>>>(
            M3, xg, nullptr, whi, wlo, l * 5 + 3, l * 5 + 4, 0, blr, nullptr, M3, NG, relu);
        xp = M1;
        xg = M3;
    }

    // ---- decoder ----
    scores_kernel<<<(E_lbl + 15) / 16, 256, 0, stream>>>(xp, xg, e_lbl, E_lbl, (float*)d_out);
}